// Round 1
// baseline (1547.885 us; speedup 1.0000x reference)
//
#include <hip/hip_runtime.h>

typedef _Float16 f16;
typedef _Float16 f16x8 __attribute__((ext_vector_type(8)));
typedef _Float16 f16x4 __attribute__((ext_vector_type(4)));
typedef float f32x4 __attribute__((ext_vector_type(4)));

constexpr int NB = 4, NT = 2048, NC = 1024, NH = 16, HS = 64;
constexpr int Mtot = NB * NT;            // 8192
constexpr int BM = 128, BN = 128, BK = 64;

// ---------------------------------------------------------------------------
// QKV GEMM: X[8192,1024] fp32 @ W[1024,3072] fp32 + bias -> Q/K/V f16 [B,H,T,64]
// ---------------------------------------------------------------------------
__global__ __launch_bounds__(256) void qkv_gemm(
    const float* __restrict__ X, const float* __restrict__ W,
    const float* __restrict__ bias,
    f16* __restrict__ Qh, f16* __restrict__ Kh, f16* __restrict__ Vh)
{
  __shared__ __align__(16) f16 As[BM * BK];
  __shared__ __align__(16) f16 Bs[BN * BK];
  const int tid = threadIdx.x;
  const int m0 = blockIdx.y * BM;
  const int n0 = blockIdx.x * BN;
  const int wave = tid >> 6, lane = tid & 63;
  const int wr = wave >> 1, wc = wave & 1;
  const int lr = lane & 15, hi = lane >> 4;

  f32x4 acc[4][4];
#pragma unroll
  for (int i = 0; i < 4; ++i)
#pragma unroll
    for (int j = 0; j < 4; ++j) acc[i][j] = (f32x4){0.f, 0.f, 0.f, 0.f};

  const int arow = tid >> 1, acg = (tid & 1) * 32;   // A: 2 thr/row, 32 cols each
  const int brow = tid >> 2, bcg = (tid & 3) * 32;   // B: 4 thr/k-row, 32 n each

  for (int k0 = 0; k0 < NC; k0 += BK) {
    // stage A (fp32 -> f16), XOR-swizzled rows
    const float* asrc = X + (size_t)(m0 + arow) * NC + k0 + acg;
#pragma unroll
    for (int i = 0; i < 8; ++i) {
      float4 v = *reinterpret_cast<const float4*>(asrc + i * 4);
      f16x4 h; h[0] = (f16)v.x; h[1] = (f16)v.y; h[2] = (f16)v.z; h[3] = (f16)v.w;
      int idx = (arow * BK + acg + i * 4) ^ ((arow & 7) << 3);
      *reinterpret_cast<f16x4*>(&As[idx]) = h;
    }
    // stage B transposed into Bs[n][k], swizzled
    const float* bsrc = W + (size_t)(k0 + brow) * (3 * NC) + n0 + bcg;
#pragma unroll
    for (int i = 0; i < 8; ++i) {
      float4 v = *reinterpret_cast<const float4*>(bsrc + i * 4);
      int n = bcg + i * 4;
      Bs[((n + 0) * BK + brow) ^ (((n + 0) & 7) << 3)] = (f16)v.x;
      Bs[((n + 1) * BK + brow) ^ (((n + 1) & 7) << 3)] = (f16)v.y;
      Bs[((n + 2) * BK + brow) ^ (((n + 2) & 7) << 3)] = (f16)v.z;
      Bs[((n + 3) * BK + brow) ^ (((n + 3) & 7) << 3)] = (f16)v.w;
    }
    __syncthreads();
#pragma unroll
    for (int kk = 0; kk < BK / 32; ++kk) {
      f16x8 a[4], b[4];
#pragma unroll
      for (int mi = 0; mi < 4; ++mi) {
        int row = wr * 64 + mi * 16 + lr;
        int idx = (row * BK + kk * 32 + hi * 8) ^ ((row & 7) << 3);
        a[mi] = *reinterpret_cast<const f16x8*>(&As[idx]);
      }
#pragma unroll
      for (int ni = 0; ni < 4; ++ni) {
        int row = wc * 64 + ni * 16 + lr;
        int idx = (row * BK + kk * 32 + hi * 8) ^ ((row & 7) << 3);
        b[ni] = *reinterpret_cast<const f16x8*>(&Bs[idx]);
      }
#pragma unroll
      for (int mi = 0; mi < 4; ++mi)
#pragma unroll
        for (int ni = 0; ni < 4; ++ni)
          acc[mi][ni] = __builtin_amdgcn_mfma_f32_16x16x32_f16(
              a[mi], b[ni], acc[mi][ni], 0, 0, 0);
    }
    __syncthreads();
  }

  // epilogue: bias + head split, f16 out
#pragma unroll
  for (int ni = 0; ni < 4; ++ni) {
    int colg = n0 + wc * 64 + ni * 16 + lr;
    int which = colg >> 10;
    int c = colg & (NC - 1);
    int h = c >> 6, d = c & 63;
    f16* dst = (which == 0) ? Qh : ((which == 1) ? Kh : Vh);
    float bv = bias[colg];
#pragma unroll
    for (int mi = 0; mi < 4; ++mi) {
#pragma unroll
      for (int r = 0; r < 4; ++r) {
        int rowg = m0 + wr * 64 + mi * 16 + hi * 4 + r;
        int b = rowg >> 11, t = rowg & (NT - 1);
        dst[(((size_t)(b * NH + h) * NT) + t) * HS + d] =
            (f16)(acc[mi][ni][r] + bv);
      }
    }
  }
}

// ---------------------------------------------------------------------------
// Flash attention (fp32 VALU), causal. One block = one (b,h) x 32-query tile.
// ---------------------------------------------------------------------------
__global__ __launch_bounds__(256) void flash_attn(
    const f16* __restrict__ Qh, const f16* __restrict__ Kh,
    const f16* __restrict__ Vh, f16* __restrict__ att)
{
  constexpr int TQ = 32, TK = 32, PD = HS + 4;   // pad 68 floats
  __shared__ __align__(16) float Qs[TQ][PD];
  __shared__ __align__(16) float Ks[TK][PD];
  __shared__ __align__(16) float Vs[TK][PD];
  __shared__ float Ps[TQ][TK + 1];
  const int tid = threadIdx.x;
  const int qt = gridDim.x - 1 - blockIdx.x;     // heavy tiles first
  const int bh = blockIdx.y;
  const f16* Qb = Qh + (size_t)bh * NT * HS;
  const f16* Kb = Kh + (size_t)bh * NT * HS;
  const f16* Vb = Vh + (size_t)bh * NT * HS;

  const int sr = tid >> 3;             // staging row 0..31
  const int sc = (tid & 7) * 8;        // staging col 0,8,..,56
  {
    union { int4 i4; f16 h[8]; } u;
    u.i4 = *reinterpret_cast<const int4*>(Qb + (size_t)(qt * TQ + sr) * HS + sc);
#pragma unroll
    for (int j = 0; j < 8; ++j) Qs[sr][sc + j] = (float)u.h[j] * 0.125f;
  }
  const int qi = tid >> 3, s = tid & 7;
  float m = -INFINITY, l = 0.f;
  float O[8];
#pragma unroll
  for (int u2 = 0; u2 < 8; ++u2) O[u2] = 0.f;

  for (int jt = 0; jt <= qt; ++jt) {
    __syncthreads();   // prev-iter reads of Ks/Vs/Ps done (also covers Q stage)
    {
      union { int4 i4; f16 h[8]; } u;
      u.i4 = *reinterpret_cast<const int4*>(Kb + (size_t)(jt * TK + sr) * HS + sc);
#pragma unroll
      for (int j = 0; j < 8; ++j) Ks[sr][sc + j] = (float)u.h[j];
      u.i4 = *reinterpret_cast<const int4*>(Vb + (size_t)(jt * TK + sr) * HS + sc);
#pragma unroll
      for (int j = 0; j < 8; ++j) Vs[sr][sc + j] = (float)u.h[j];
    }
    __syncthreads();

    // scores for keys kj = s, s+8, s+16, s+24 (conflict-friendly stride)
    float s0 = 0, s1 = 0, s2 = 0, s3 = 0;
#pragma unroll
    for (int d = 0; d < HS; d += 4) {
      float4 q4 = *reinterpret_cast<const float4*>(&Qs[qi][d]);
      float4 k0 = *reinterpret_cast<const float4*>(&Ks[s][d]);
      float4 k1 = *reinterpret_cast<const float4*>(&Ks[s + 8][d]);
      float4 k2 = *reinterpret_cast<const float4*>(&Ks[s + 16][d]);
      float4 k3 = *reinterpret_cast<const float4*>(&Ks[s + 24][d]);
      s0 += q4.x * k0.x + q4.y * k0.y + q4.z * k0.z + q4.w * k0.w;
      s1 += q4.x * k1.x + q4.y * k1.y + q4.z * k1.z + q4.w * k1.w;
      s2 += q4.x * k2.x + q4.y * k2.y + q4.z * k2.z + q4.w * k2.w;
      s3 += q4.x * k3.x + q4.y * k3.y + q4.z * k3.z + q4.w * k3.w;
    }
    if (jt == qt) {                    // causal mask on diagonal tile
      if (s      > qi) s0 = -INFINITY;
      if (s + 8  > qi) s1 = -INFINITY;
      if (s + 16 > qi) s2 = -INFINITY;
      if (s + 24 > qi) s3 = -INFINITY;
    }
    float tm = fmaxf(fmaxf(s0, s1), fmaxf(s2, s3));
#pragma unroll
    for (int off = 1; off < 8; off <<= 1) tm = fmaxf(tm, __shfl_xor(tm, off, 8));
    float mn = fmaxf(m, tm);
    float alpha = __expf(m - mn);
    float p0 = __expf(s0 - mn);
    float p1 = __expf(s1 - mn);
    float p2 = __expf(s2 - mn);
    float p3 = __expf(s3 - mn);
    float ts = p0 + p1 + p2 + p3;
#pragma unroll
    for (int off = 1; off < 8; off <<= 1) ts += __shfl_xor(ts, off, 8);
    l = l * alpha + ts;
    m = mn;
    Ps[qi][s] = p0; Ps[qi][s + 8] = p1; Ps[qi][s + 16] = p2; Ps[qi][s + 24] = p3;
#pragma unroll
    for (int u2 = 0; u2 < 8; ++u2) O[u2] *= alpha;
    __syncthreads();   // Ps visible, Vs ready
#pragma unroll
    for (int kj = 0; kj < TK; ++kj) {
      float w = Ps[qi][kj];
      float4 v0 = *reinterpret_cast<const float4*>(&Vs[kj][s * 8]);
      float4 v1 = *reinterpret_cast<const float4*>(&Vs[kj][s * 8 + 4]);
      O[0] += w * v0.x; O[1] += w * v0.y; O[2] += w * v0.z; O[3] += w * v0.w;
      O[4] += w * v1.x; O[5] += w * v1.y; O[6] += w * v1.z; O[7] += w * v1.w;
    }
  }
  float inv = 1.f / l;
  const int b = bh >> 4, h = bh & (NH - 1);
  const int t = qt * TQ + qi;
  union { int4 i4; f16 hh[8]; } o;
#pragma unroll
  for (int u2 = 0; u2 < 8; ++u2) o.hh[u2] = (f16)(O[u2] * inv);
  *reinterpret_cast<int4*>(&att[((size_t)(b * NT + t)) * NC + h * HS + s * 8]) = o.i4;
}

// ---------------------------------------------------------------------------
// Proj GEMM: att[8192,1024] f16 @ Wproj[1024,1024] fp32 + bias -> out fp32
// ---------------------------------------------------------------------------
__global__ __launch_bounds__(256) void proj_gemm(
    const f16* __restrict__ A, const float* __restrict__ W,
    const float* __restrict__ bias, float* __restrict__ Out)
{
  __shared__ __align__(16) f16 As[BM * BK];
  __shared__ __align__(16) f16 Bs[BN * BK];
  const int tid = threadIdx.x;
  const int m0 = blockIdx.y * BM;
  const int n0 = blockIdx.x * BN;
  const int wave = tid >> 6, lane = tid & 63;
  const int wr = wave >> 1, wc = wave & 1;
  const int lr = lane & 15, hi = lane >> 4;

  f32x4 acc[4][4];
#pragma unroll
  for (int i = 0; i < 4; ++i)
#pragma unroll
    for (int j = 0; j < 4; ++j) acc[i][j] = (f32x4){0.f, 0.f, 0.f, 0.f};

  const int arow = tid >> 1, acg = (tid & 1) * 32;
  const int brow = tid >> 2, bcg = (tid & 3) * 32;

  for (int k0 = 0; k0 < NC; k0 += BK) {
    const f16* asrc = A + (size_t)(m0 + arow) * NC + k0 + acg;
#pragma unroll
    for (int i = 0; i < 4; ++i) {
      f16x8 v = *reinterpret_cast<const f16x8*>(asrc + i * 8);
      int idx = (arow * BK + acg + i * 8) ^ ((arow & 7) << 3);
      *reinterpret_cast<f16x8*>(&As[idx]) = v;
    }
    const float* bsrc = W + (size_t)(k0 + brow) * NC + n0 + bcg;
#pragma unroll
    for (int i = 0; i < 8; ++i) {
      float4 v = *reinterpret_cast<const float4*>(bsrc + i * 4);
      int n = bcg + i * 4;
      Bs[((n + 0) * BK + brow) ^ (((n + 0) & 7) << 3)] = (f16)v.x;
      Bs[((n + 1) * BK + brow) ^ (((n + 1) & 7) << 3)] = (f16)v.y;
      Bs[((n + 2) * BK + brow) ^ (((n + 2) & 7) << 3)] = (f16)v.z;
      Bs[((n + 3) * BK + brow) ^ (((n + 3) & 7) << 3)] = (f16)v.w;
    }
    __syncthreads();
#pragma unroll
    for (int kk = 0; kk < BK / 32; ++kk) {
      f16x8 a[4], b[4];
#pragma unroll
      for (int mi = 0; mi < 4; ++mi) {
        int row = wr * 64 + mi * 16 + lr;
        int idx = (row * BK + kk * 32 + hi * 8) ^ ((row & 7) << 3);
        a[mi] = *reinterpret_cast<const f16x8*>(&As[idx]);
      }
#pragma unroll
      for (int ni = 0; ni < 4; ++ni) {
        int row = wc * 64 + ni * 16 + lr;
        int idx = (row * BK + kk * 32 + hi * 8) ^ ((row & 7) << 3);
        b[ni] = *reinterpret_cast<const f16x8*>(&Bs[idx]);
      }
#pragma unroll
      for (int mi = 0; mi < 4; ++mi)
#pragma unroll
        for (int ni = 0; ni < 4; ++ni)
          acc[mi][ni] = __builtin_amdgcn_mfma_f32_16x16x32_f16(
              a[mi], b[ni], acc[mi][ni], 0, 0, 0);
    }
    __syncthreads();
  }

#pragma unroll
  for (int ni = 0; ni < 4; ++ni) {
    int colg = n0 + wc * 64 + ni * 16 + lr;
    float bv = bias[colg];
#pragma unroll
    for (int mi = 0; mi < 4; ++mi) {
#pragma unroll
      for (int r = 0; r < 4; ++r) {
        int rowg = m0 + wr * 64 + mi * 16 + hi * 4 + r;
        Out[(size_t)rowg * NC + colg] = acc[mi][ni][r] + bv;
      }
    }
  }
}

// ---------------------------------------------------------------------------
extern "C" void kernel_launch(void* const* d_in, const int* in_sizes, int n_in,
                              void* d_out, int out_size, void* d_ws, size_t ws_size,
                              hipStream_t stream)
{
  (void)in_sizes; (void)n_in; (void)out_size; (void)ws_size;
  const float* x     = (const float*)d_in[0];
  const float* Wqkv  = (const float*)d_in[1];
  const float* bqkv  = (const float*)d_in[2];
  const float* Wproj = (const float*)d_in[3];
  const float* bproj = (const float*)d_in[4];
  float* out = (float*)d_out;

  const size_t HE = (size_t)NB * NH * NT * HS;   // 8388608 elems per tensor
  f16* Qh  = (f16*)d_ws;
  f16* Kh  = Qh + HE;
  f16* Vh  = Kh + HE;
  f16* att = Vh + HE;

  qkv_gemm<<<dim3(3 * NC / BN, Mtot / BM), 256, 0, stream>>>(x, Wqkv, bqkv, Qh, Kh, Vh);
  flash_attn<<<dim3(NT / 32, NB * NH), 256, 0, stream>>>(Qh, Kh, Vh, att);
  proj_gemm<<<dim3(NC / BN, Mtot / BM), 256, 0, stream>>>(att, Wproj, bproj, out);
}

// Round 2
// 521.614 us; speedup vs baseline: 2.9675x; 2.9675x over previous
//
#include <hip/hip_runtime.h>

typedef _Float16 f16;
typedef _Float16 f16x8 __attribute__((ext_vector_type(8)));
typedef _Float16 f16x4 __attribute__((ext_vector_type(4)));
typedef float f32x4 __attribute__((ext_vector_type(4)));

constexpr int NB = 4, NT = 2048, NC = 1024, NH = 16, HS = 64;
constexpr int Mtot = NB * NT;            // 8192
constexpr int BM = 128, BN = 128, BK = 64;

// ---------------------------------------------------------------------------
// QKV GEMM: X[8192,1024] fp32 @ W[1024,3072] fp32 + bias -> Q/K/V f16 [B,H,T,64]
// ---------------------------------------------------------------------------
__global__ __launch_bounds__(256) void qkv_gemm(
    const float* __restrict__ X, const float* __restrict__ W,
    const float* __restrict__ bias,
    f16* __restrict__ Qh, f16* __restrict__ Kh, f16* __restrict__ Vh)
{
  __shared__ __align__(16) f16 As[BM * BK];
  __shared__ __align__(16) f16 Bs[BN * BK];
  const int tid = threadIdx.x;
  const int m0 = blockIdx.y * BM;
  const int n0 = blockIdx.x * BN;
  const int wave = tid >> 6, lane = tid & 63;
  const int wr = wave >> 1, wc = wave & 1;
  const int lr = lane & 15, hi = lane >> 4;

  f32x4 acc[4][4];
#pragma unroll
  for (int i = 0; i < 4; ++i)
#pragma unroll
    for (int j = 0; j < 4; ++j) acc[i][j] = (f32x4){0.f, 0.f, 0.f, 0.f};

  const int arow = tid >> 1, acg = (tid & 1) * 32;   // A: 2 thr/row, 32 cols each
  const int brow = tid >> 2, bcg = (tid & 3) * 32;   // B: 4 thr/k-row, 32 n each

  for (int k0 = 0; k0 < NC; k0 += BK) {
    const float* asrc = X + (size_t)(m0 + arow) * NC + k0 + acg;
#pragma unroll
    for (int i = 0; i < 8; ++i) {
      float4 v = *reinterpret_cast<const float4*>(asrc + i * 4);
      f16x4 h; h[0] = (f16)v.x; h[1] = (f16)v.y; h[2] = (f16)v.z; h[3] = (f16)v.w;
      int idx = (arow * BK + acg + i * 4) ^ ((arow & 7) << 3);
      *reinterpret_cast<f16x4*>(&As[idx]) = h;
    }
    const float* bsrc = W + (size_t)(k0 + brow) * (3 * NC) + n0 + bcg;
#pragma unroll
    for (int i = 0; i < 8; ++i) {
      float4 v = *reinterpret_cast<const float4*>(bsrc + i * 4);
      int n = bcg + i * 4;
      Bs[((n + 0) * BK + brow) ^ (((n + 0) & 7) << 3)] = (f16)v.x;
      Bs[((n + 1) * BK + brow) ^ (((n + 1) & 7) << 3)] = (f16)v.y;
      Bs[((n + 2) * BK + brow) ^ (((n + 2) & 7) << 3)] = (f16)v.z;
      Bs[((n + 3) * BK + brow) ^ (((n + 3) & 7) << 3)] = (f16)v.w;
    }
    __syncthreads();
#pragma unroll
    for (int kk = 0; kk < BK / 32; ++kk) {
      f16x8 a[4], b[4];
#pragma unroll
      for (int mi = 0; mi < 4; ++mi) {
        int row = wr * 64 + mi * 16 + lr;
        int idx = (row * BK + kk * 32 + hi * 8) ^ ((row & 7) << 3);
        a[mi] = *reinterpret_cast<const f16x8*>(&As[idx]);
      }
#pragma unroll
      for (int ni = 0; ni < 4; ++ni) {
        int row = wc * 64 + ni * 16 + lr;
        int idx = (row * BK + kk * 32 + hi * 8) ^ ((row & 7) << 3);
        b[ni] = *reinterpret_cast<const f16x8*>(&Bs[idx]);
      }
#pragma unroll
      for (int mi = 0; mi < 4; ++mi)
#pragma unroll
        for (int ni = 0; ni < 4; ++ni)
          acc[mi][ni] = __builtin_amdgcn_mfma_f32_16x16x32_f16(
              a[mi], b[ni], acc[mi][ni], 0, 0, 0);
    }
    __syncthreads();
  }

#pragma unroll
  for (int ni = 0; ni < 4; ++ni) {
    int colg = n0 + wc * 64 + ni * 16 + lr;
    int which = colg >> 10;
    int c = colg & (NC - 1);
    int h = c >> 6, d = c & 63;
    f16* dst = (which == 0) ? Qh : ((which == 1) ? Kh : Vh);
    float bv = bias[colg];
#pragma unroll
    for (int mi = 0; mi < 4; ++mi) {
#pragma unroll
      for (int r = 0; r < 4; ++r) {
        int rowg = m0 + wr * 64 + mi * 16 + hi * 4 + r;
        int b = rowg >> 11, t = rowg & (NT - 1);
        dst[(((size_t)(b * NH + h) * NT) + t) * HS + d] =
            (f16)(acc[mi][ni][r] + bv);
      }
    }
  }
}

// ---------------------------------------------------------------------------
// MFMA flash attention, causal. Block = 4 waves x 128 q-rows, KV tile = 64.
// ---------------------------------------------------------------------------
__global__ __launch_bounds__(256) void flash_attn(
    const f16* __restrict__ Qh, const f16* __restrict__ Kh,
    const f16* __restrict__ Vh, f16* __restrict__ att)
{
  __shared__ __align__(16) f16 Ks[64 * 64];        // K tile, row-major [kv][d], d-swizzled
  __shared__ __align__(16) f16 Vt[64 * 64];        // V tile transposed [d][kv], kv-swizzled
  __shared__ __align__(16) f16 Ps[4][32 * 72];     // per-wave P / O staging, stride 72

  const int tid = threadIdx.x;
  const int w = tid >> 6, l = tid & 63;
  const int lr = l & 15, g = l >> 4;
  const int qt = (gridDim.x - 1) - blockIdx.x;     // heavy tiles first
  const int bh = blockIdx.y;
  const int qbase = qt * 128 + w * 32;
  const f16* Qb = Qh + (size_t)bh * NT * HS;
  const f16* Kb = Kh + (size_t)bh * NT * HS;
  const f16* Vb = Vh + (size_t)bh * NT * HS;

  // Q fragments in registers (A layout: row = lr, k = g*8+j), pre-scaled 1/8
  f16x8 qA[2][2];
#pragma unroll
  for (int mt = 0; mt < 2; ++mt)
#pragma unroll
    for (int kt = 0; kt < 2; ++kt) {
      f16x8 v = *reinterpret_cast<const f16x8*>(
          Qb + (size_t)(qbase + 16 * mt + lr) * HS + 32 * kt + 8 * g);
#pragma unroll
      for (int j = 0; j < 8; ++j) v[j] = v[j] * (f16)0.125f;
      qA[mt][kt] = v;
    }

  f32x4 O[2][4];
  float mrow[2][4], lrow[2][4];
#pragma unroll
  for (int mt = 0; mt < 2; ++mt) {
#pragma unroll
    for (int dt = 0; dt < 4; ++dt) O[mt][dt] = (f32x4){0.f, 0.f, 0.f, 0.f};
#pragma unroll
    for (int r = 0; r < 4; ++r) { mrow[mt][r] = -INFINITY; lrow[mt][r] = 0.f; }
  }

  const int srow = tid >> 3;          // 0..31
  const int scol = (tid & 7) * 8;     // 0..56

  const int jtmax = 2 * qt + 1;
  for (int jt = 0; jt <= jtmax; ++jt) {
    __syncthreads();                  // prior tile's reads complete
#pragma unroll
    for (int half = 0; half < 2; ++half) {
      int row = srow + 32 * half;
      f16x8 kv = *reinterpret_cast<const f16x8*>(
          Kb + (size_t)(jt * 64 + row) * HS + scol);
      *reinterpret_cast<f16x8*>(&Ks[row * 64 + (scol ^ ((row & 7) << 3))]) = kv;
      f16x8 vv = *reinterpret_cast<const f16x8*>(
          Vb + (size_t)(jt * 64 + row) * HS + scol);
#pragma unroll
      for (int j = 0; j < 8; ++j) {
        int d = scol + j;
        int s = (d + (d >> 3)) & 7;
        Vt[d * 64 + (row ^ (s << 3))] = vv[j];
      }
    }
    __syncthreads();

    if (jt * 64 > qbase + 31) continue;   // this wave fully masked for tile

    // ---- QK^T: S[32 q][64 kv] ----
    f32x4 S[2][4];
#pragma unroll
    for (int mt = 0; mt < 2; ++mt)
#pragma unroll
      for (int nt = 0; nt < 4; ++nt) S[mt][nt] = (f32x4){0.f, 0.f, 0.f, 0.f};
#pragma unroll
    for (int kt = 0; kt < 2; ++kt)
#pragma unroll
      for (int nt = 0; nt < 4; ++nt) {
        f16x8 kB = *reinterpret_cast<const f16x8*>(
            &Ks[(16 * nt + lr) * 64 + ((32 * kt + 8 * g) ^ ((lr & 7) << 3))]);
#pragma unroll
        for (int mt = 0; mt < 2; ++mt)
          S[mt][nt] = __builtin_amdgcn_mfma_f32_16x16x32_f16(
              qA[mt][kt], kB, S[mt][nt], 0, 0, 0);
      }

    // ---- online softmax (C layout: row = g*4+r, col = lr) ----
    const bool needMask = (jt * 64 + 63) > qbase;
    float p[2][4][4];
#pragma unroll
    for (int mt = 0; mt < 2; ++mt)
#pragma unroll
      for (int r = 0; r < 4; ++r) {
        int qg = qbase + 16 * mt + 4 * g + r;
        float sv[4];
#pragma unroll
        for (int nt = 0; nt < 4; ++nt) {
          sv[nt] = S[mt][nt][r];
          if (needMask && (jt * 64 + 16 * nt + lr) > qg) sv[nt] = -INFINITY;
        }
        float tm = fmaxf(fmaxf(sv[0], sv[1]), fmaxf(sv[2], sv[3]));
#pragma unroll
        for (int off = 1; off < 16; off <<= 1) tm = fmaxf(tm, __shfl_xor(tm, off));
        float mo = mrow[mt][r];
        float mn = fmaxf(mo, tm);
        float al = __expf(mo - mn);
        mrow[mt][r] = mn;
        float ts = 0.f;
#pragma unroll
        for (int nt = 0; nt < 4; ++nt) {
          float pv = __expf(sv[nt] - mn);
          p[mt][nt][r] = pv;
          ts += pv;
        }
#pragma unroll
        for (int off = 1; off < 16; off <<= 1) ts += __shfl_xor(ts, off);
        lrow[mt][r] = lrow[mt][r] * al + ts;
#pragma unroll
        for (int dt = 0; dt < 4; ++dt) O[mt][dt][r] *= al;
      }

    // ---- P transpose via per-wave LDS (C layout -> A layout) ----
#pragma unroll
    for (int mt = 0; mt < 2; ++mt)
#pragma unroll
      for (int nt = 0; nt < 4; ++nt)
#pragma unroll
        for (int r = 0; r < 4; ++r)
          Ps[w][(16 * mt + 4 * g + r) * 72 + 16 * nt + lr] = (f16)p[mt][nt][r];

    // ---- PV: O += P[32 q][64 kv] @ V[64 kv][64 d] ----
#pragma unroll
    for (int kt = 0; kt < 2; ++kt) {
      f16x8 pA[2];
#pragma unroll
      for (int mt = 0; mt < 2; ++mt)
        pA[mt] = *reinterpret_cast<const f16x8*>(
            &Ps[w][(16 * mt + lr) * 72 + 32 * kt + 8 * g]);
#pragma unroll
      for (int dt = 0; dt < 4; ++dt) {
        int d = 16 * dt + lr;
        int sw = (d + (d >> 3)) & 7;
        f16x8 vB = *reinterpret_cast<const f16x8*>(
            &Vt[d * 64 + ((32 * kt + 8 * g) ^ (sw << 3))]);
#pragma unroll
        for (int mt = 0; mt < 2; ++mt)
          O[mt][dt] = __builtin_amdgcn_mfma_f32_16x16x32_f16(
              pA[mt], vB, O[mt][dt], 0, 0, 0);
      }
    }
  }

  // ---- finalize: normalize, repack via Ps, coalesced f16x8 stores ----
#pragma unroll
  for (int mt = 0; mt < 2; ++mt) {
    float inv[4];
#pragma unroll
    for (int r = 0; r < 4; ++r) inv[r] = 1.f / lrow[mt][r];
#pragma unroll
    for (int dt = 0; dt < 4; ++dt)
#pragma unroll
      for (int r = 0; r < 4; ++r)
        Ps[w][(16 * mt + 4 * g + r) * 72 + 16 * dt + lr] =
            (f16)(O[mt][dt][r] * inv[r]);
  }
  const int orow = l >> 1;
  const int ocol = (l & 1) * 32;
  const int b = bh >> 4, h = bh & (NH - 1);
#pragma unroll
  for (int i = 0; i < 4; ++i) {
    f16x8 ov = *reinterpret_cast<const f16x8*>(&Ps[w][orow * 72 + ocol + i * 8]);
    *reinterpret_cast<f16x8*>(
        &att[((size_t)(b * NT + qbase + orow)) * NC + h * HS + ocol + i * 8]) = ov;
  }
}

// ---------------------------------------------------------------------------
// Proj GEMM: att[8192,1024] f16 @ Wproj[1024,1024] fp32 + bias -> out fp32
// ---------------------------------------------------------------------------
__global__ __launch_bounds__(256) void proj_gemm(
    const f16* __restrict__ A, const float* __restrict__ W,
    const float* __restrict__ bias, float* __restrict__ Out)
{
  __shared__ __align__(16) f16 As[BM * BK];
  __shared__ __align__(16) f16 Bs[BN * BK];
  const int tid = threadIdx.x;
  const int m0 = blockIdx.y * BM;
  const int n0 = blockIdx.x * BN;
  const int wave = tid >> 6, lane = tid & 63;
  const int wr = wave >> 1, wc = wave & 1;
  const int lr = lane & 15, hi = lane >> 4;

  f32x4 acc[4][4];
#pragma unroll
  for (int i = 0; i < 4; ++i)
#pragma unroll
    for (int j = 0; j < 4; ++j) acc[i][j] = (f32x4){0.f, 0.f, 0.f, 0.f};

  const int arow = tid >> 1, acg = (tid & 1) * 32;
  const int brow = tid >> 2, bcg = (tid & 3) * 32;

  for (int k0 = 0; k0 < NC; k0 += BK) {
    const f16* asrc = A + (size_t)(m0 + arow) * NC + k0 + acg;
#pragma unroll
    for (int i = 0; i < 4; ++i) {
      f16x8 v = *reinterpret_cast<const f16x8*>(asrc + i * 8);
      int idx = (arow * BK + acg + i * 8) ^ ((arow & 7) << 3);
      *reinterpret_cast<f16x8*>(&As[idx]) = v;
    }
    const float* bsrc = W + (size_t)(k0 + brow) * NC + n0 + bcg;
#pragma unroll
    for (int i = 0; i < 8; ++i) {
      float4 v = *reinterpret_cast<const float4*>(bsrc + i * 4);
      int n = bcg + i * 4;
      Bs[((n + 0) * BK + brow) ^ (((n + 0) & 7) << 3)] = (f16)v.x;
      Bs[((n + 1) * BK + brow) ^ (((n + 1) & 7) << 3)] = (f16)v.y;
      Bs[((n + 2) * BK + brow) ^ (((n + 2) & 7) << 3)] = (f16)v.z;
      Bs[((n + 3) * BK + brow) ^ (((n + 3) & 7) << 3)] = (f16)v.w;
    }
    __syncthreads();
#pragma unroll
    for (int kk = 0; kk < BK / 32; ++kk) {
      f16x8 a[4], b[4];
#pragma unroll
      for (int mi = 0; mi < 4; ++mi) {
        int row = wr * 64 + mi * 16 + lr;
        int idx = (row * BK + kk * 32 + hi * 8) ^ ((row & 7) << 3);
        a[mi] = *reinterpret_cast<const f16x8*>(&As[idx]);
      }
#pragma unroll
      for (int ni = 0; ni < 4; ++ni) {
        int row = wc * 64 + ni * 16 + lr;
        int idx = (row * BK + kk * 32 + hi * 8) ^ ((row & 7) << 3);
        b[ni] = *reinterpret_cast<const f16x8*>(&Bs[idx]);
      }
#pragma unroll
      for (int mi = 0; mi < 4; ++mi)
#pragma unroll
        for (int ni = 0; ni < 4; ++ni)
          acc[mi][ni] = __builtin_amdgcn_mfma_f32_16x16x32_f16(
              a[mi], b[ni], acc[mi][ni], 0, 0, 0);
    }
    __syncthreads();
  }

#pragma unroll
  for (int ni = 0; ni < 4; ++ni) {
    int colg = n0 + wc * 64 + ni * 16 + lr;
    float bv = bias[colg];
#pragma unroll
    for (int mi = 0; mi < 4; ++mi) {
#pragma unroll
      for (int r = 0; r < 4; ++r) {
        int rowg = m0 + wr * 64 + mi * 16 + hi * 4 + r;
        Out[(size_t)rowg * NC + colg] = acc[mi][ni][r] + bv;
      }
    }
  }
}

// ---------------------------------------------------------------------------
extern "C" void kernel_launch(void* const* d_in, const int* in_sizes, int n_in,
                              void* d_out, int out_size, void* d_ws, size_t ws_size,
                              hipStream_t stream)
{
  (void)in_sizes; (void)n_in; (void)out_size; (void)ws_size;
  const float* x     = (const float*)d_in[0];
  const float* Wqkv  = (const float*)d_in[1];
  const float* bqkv  = (const float*)d_in[2];
  const float* Wproj = (const float*)d_in[3];
  const float* bproj = (const float*)d_in[4];
  float* out = (float*)d_out;

  const size_t HE = (size_t)NB * NH * NT * HS;   // 8388608 elems per tensor
  f16* Qh  = (f16*)d_ws;
  f16* Kh  = Qh + HE;
  f16* Vh  = Kh + HE;
  f16* att = Vh + HE;

  qkv_gemm<<<dim3(3 * NC / BN, Mtot / BM), 256, 0, stream>>>(x, Wqkv, bqkv, Qh, Kh, Vh);
  flash_attn<<<dim3(NT / 128, NB * NH), 256, 0, stream>>>(Qh, Kh, Vh, att);
  proj_gemm<<<dim3(NC / BN, Mtot / BM), 256, 0, stream>>>(att, Wproj, bproj, out);
}

// Round 3
// 518.704 us; speedup vs baseline: 2.9841x; 1.0056x over previous
//
#include <hip/hip_runtime.h>

typedef _Float16 f16;
typedef _Float16 f16x4 __attribute__((ext_vector_type(4)));
typedef _Float16 f16x8 __attribute__((ext_vector_type(8)));
typedef float f32x4 __attribute__((ext_vector_type(4)));

constexpr int NB = 4, NT = 2048, NC = 1024, NH = 16, HS = 64;
constexpr int Mtot = NB * NT;            // 8192
constexpr int BM = 128, BN = 128, BK = 64;

__device__ __forceinline__ int bswz(int n) { return ((n + 2 * (n >> 5)) & 7) << 3; }

// ---------------------------------------------------------------------------
// QKV GEMM: X[8192,1024] fp32 @ W[1024,3072] fp32 + bias -> Q/K/V f16 [B,H,T,64]
// ---------------------------------------------------------------------------
__global__ __launch_bounds__(256) void qkv_gemm(
    const float* __restrict__ X, const float* __restrict__ W,
    const float* __restrict__ bias,
    f16* __restrict__ Qh, f16* __restrict__ Kh, f16* __restrict__ Vh)
{
  __shared__ __align__(16) f16 As[BM * BK];
  __shared__ __align__(16) f16 Bs[BN * BK];
  const int tid = threadIdx.x;
  const int flat = blockIdx.y * gridDim.x + blockIdx.x;        // 0..1535
  const int v = (flat & 7) * 192 + (flat >> 3);                // XCD-contig
  const int m0 = (v / 24) * BM;
  const int n0 = (v % 24) * BN;
  const int wave = tid >> 6, lane = tid & 63;
  const int wr = wave >> 1, wc = wave & 1;
  const int lr = lane & 15, hi = lane >> 4;

  f32x4 acc[4][4];
#pragma unroll
  for (int i = 0; i < 4; ++i)
#pragma unroll
    for (int j = 0; j < 4; ++j) acc[i][j] = (f32x4){0.f, 0.f, 0.f, 0.f};

  const int arow = tid >> 1, acg = (tid & 1) * 32;   // A: 2 thr/row, 32 cols each
  const int brow = tid >> 2, bcg = (tid & 3) * 32;   // B: 4 thr/k-row, 32 n each

  for (int k0 = 0; k0 < NC; k0 += BK) {
    const float* asrc = X + (size_t)(m0 + arow) * NC + k0 + acg;
#pragma unroll
    for (int i = 0; i < 8; ++i) {
      float4 vv = *reinterpret_cast<const float4*>(asrc + i * 4);
      f16x4 h; h[0] = (f16)vv.x; h[1] = (f16)vv.y; h[2] = (f16)vv.z; h[3] = (f16)vv.w;
      int idx = (arow * BK + acg + i * 4) ^ ((arow & 7) << 3);
      *reinterpret_cast<f16x4*>(&As[idx]) = h;
    }
    const float* bsrc = W + (size_t)(k0 + brow) * (3 * NC) + n0 + bcg;
#pragma unroll
    for (int i = 0; i < 8; ++i) {
      float4 vv = *reinterpret_cast<const float4*>(bsrc + i * 4);
      int n = bcg + i * 4;
      Bs[((n + 0) * BK + brow) ^ bswz(n + 0)] = (f16)vv.x;
      Bs[((n + 1) * BK + brow) ^ bswz(n + 1)] = (f16)vv.y;
      Bs[((n + 2) * BK + brow) ^ bswz(n + 2)] = (f16)vv.z;
      Bs[((n + 3) * BK + brow) ^ bswz(n + 3)] = (f16)vv.w;
    }
    __syncthreads();
#pragma unroll
    for (int kk = 0; kk < BK / 32; ++kk) {
      f16x8 a[4], b[4];
#pragma unroll
      for (int mi = 0; mi < 4; ++mi) {
        int row = wr * 64 + mi * 16 + lr;
        int idx = (row * BK + kk * 32 + hi * 8) ^ ((row & 7) << 3);
        a[mi] = *reinterpret_cast<const f16x8*>(&As[idx]);
      }
#pragma unroll
      for (int ni = 0; ni < 4; ++ni) {
        int row = wc * 64 + ni * 16 + lr;
        int idx = (row * BK + kk * 32 + hi * 8) ^ bswz(row);
        b[ni] = *reinterpret_cast<const f16x8*>(&Bs[idx]);
      }
#pragma unroll
      for (int mi = 0; mi < 4; ++mi)
#pragma unroll
        for (int ni = 0; ni < 4; ++ni)
          acc[mi][ni] = __builtin_amdgcn_mfma_f32_16x16x32_f16(
              a[mi], b[ni], acc[mi][ni], 0, 0, 0);
    }
    __syncthreads();
  }

#pragma unroll
  for (int ni = 0; ni < 4; ++ni) {
    int colg = n0 + wc * 64 + ni * 16 + lr;
    int which = colg >> 10;
    int c = colg & (NC - 1);
    int h = c >> 6, d = c & 63;
    f16* dst = (which == 0) ? Qh : ((which == 1) ? Kh : Vh);
    float bv = bias[colg];
#pragma unroll
    for (int mi = 0; mi < 4; ++mi) {
#pragma unroll
      for (int r = 0; r < 4; ++r) {
        int rowg = m0 + wr * 64 + mi * 16 + hi * 4 + r;
        int b = rowg >> 11, t = rowg & (NT - 1);
        dst[(((size_t)(b * NH + h) * NT) + t) * HS + d] =
            (f16)(acc[mi][ni][r] + bv);
      }
    }
  }
}

// ---------------------------------------------------------------------------
// MFMA flash attention, causal. Block = 8 waves x 256 q-rows, KV tile = 64,
// double-buffered K/V staging, swapped QK^T (St = K·Q^T), one barrier/tile.
// ---------------------------------------------------------------------------
__global__ __launch_bounds__(512, 4) void flash_attn(
    const f16* __restrict__ Qh, const f16* __restrict__ Kh,
    const f16* __restrict__ Vh, f16* __restrict__ att)
{
  __shared__ __align__(16) f16 Ks[2][64 * 64];   // [kv][d], d-swizzled by row
  __shared__ __align__(16) f16 Vt[2][64 * 64];   // [d][kv], kv-swizzled by d
  __shared__ __align__(16) f16 Ps[8][32 * 64];   // per-wave [q][kv|d], col-swizzled by q

  const int tid = threadIdx.x;
  const int w = tid >> 6, l = tid & 63;
  const int lr = l & 15, g = l >> 4;

  const int flat = blockIdx.y * gridDim.x + blockIdx.x;   // 0..511
  const int v = (flat & 7) * 64 + (flat >> 3);            // XCD-contig chunks
  const int qt = 7 - (v & 7);                             // heavy-first
  const int bh = v >> 3;

  const int qbase = qt * 256 + w * 32;
  const f16* Qb = Qh + (size_t)bh * NT * HS;
  const f16* Kb = Kh + (size_t)bh * NT * HS;
  const f16* Vb = Vh + (size_t)bh * NT * HS;

  // Q as B-operand fragments (col=lr, k=8g+j), scale (1/8)*log2(e) folded in
  f16x8 qB[2][2];
#pragma unroll
  for (int mt = 0; mt < 2; ++mt)
#pragma unroll
    for (int ds = 0; ds < 2; ++ds) {
      f16x8 t = *reinterpret_cast<const f16x8*>(
          Qb + (size_t)(qbase + 16 * mt + lr) * HS + 32 * ds + 8 * g);
#pragma unroll
      for (int j = 0; j < 8; ++j) t[j] = t[j] * (f16)0.18033688f;
      qB[mt][ds] = t;
    }

  f32x4 Ot[2][4];                       // O^T: [q-tile mt][d-tile dt], col=q=lr
  float m_run[2], l_run[2];
#pragma unroll
  for (int mt = 0; mt < 2; ++mt) {
#pragma unroll
    for (int dt = 0; dt < 4; ++dt) Ot[mt][dt] = (f32x4){0.f, 0.f, 0.f, 0.f};
    m_run[mt] = -INFINITY; l_run[mt] = 0.f;
  }

  const int srow = tid >> 3;            // 0..63
  const int scol = (tid & 7) * 8;       // 0..56
  const int jtmax = 4 * qt + 3;

  f16x8 kpre = *reinterpret_cast<const f16x8*>(Kb + (size_t)srow * HS + scol);
  f16x8 vpre = *reinterpret_cast<const f16x8*>(Vb + (size_t)srow * HS + scol);

  for (int jt = 0; jt <= jtmax; ++jt) {
    const int cur = jt & 1;
    // ---- commit prefetched tile to LDS ----
    *reinterpret_cast<f16x8*>(&Ks[cur][srow * 64 + (scol ^ ((srow & 7) << 3))]) = kpre;
#pragma unroll
    for (int j = 0; j < 8; ++j) {
      int d = scol + j;
      int s = (d + (d >> 3)) & 7;
      Vt[cur][d * 64 + (srow ^ (s << 3))] = vpre[j];
    }
    // ---- issue next tile's global loads (latency hides under compute) ----
    if (jt < jtmax) {
      kpre = *reinterpret_cast<const f16x8*>(Kb + (size_t)((jt + 1) * 64 + srow) * HS + scol);
      vpre = *reinterpret_cast<const f16x8*>(Vb + (size_t)((jt + 1) * 64 + srow) * HS + scol);
    }
    __syncthreads();

    if (jt * 64 > qbase + 31) continue;   // wave fully masked for this tile

    // ---- St = K·Q^T : [64 kv][32 q] ----
    f32x4 St[4][2];
#pragma unroll
    for (int kt2 = 0; kt2 < 4; ++kt2)
#pragma unroll
      for (int mt = 0; mt < 2; ++mt) St[kt2][mt] = (f32x4){0.f, 0.f, 0.f, 0.f};
    __builtin_amdgcn_s_setprio(1);
#pragma unroll
    for (int kt2 = 0; kt2 < 4; ++kt2) {
      int row = 16 * kt2 + lr;
#pragma unroll
      for (int ds = 0; ds < 2; ++ds) {
        f16x8 aK = *reinterpret_cast<const f16x8*>(
            &Ks[cur][row * 64 + ((32 * ds + 8 * g) ^ ((row & 7) << 3))]);
#pragma unroll
        for (int mt = 0; mt < 2; ++mt)
          St[kt2][mt] = __builtin_amdgcn_mfma_f32_16x16x32_f16(
              aK, qB[mt][ds], St[kt2][mt], 0, 0, 0);
      }
    }
    __builtin_amdgcn_s_setprio(0);

    // ---- online softmax on St columns (q = 16mt+lr), rows kv = 16kt2+4g+r ----
    const bool needMask = (jt * 64 + 63) > qbase;
#pragma unroll
    for (int mt = 0; mt < 2; ++mt) {
      const int qg = qbase + 16 * mt + lr;
      if (needMask) {
#pragma unroll
        for (int kt2 = 0; kt2 < 4; ++kt2)
#pragma unroll
          for (int r = 0; r < 4; ++r)
            if ((jt * 64 + 16 * kt2 + 4 * g + r) > qg) St[kt2][mt][r] = -INFINITY;
      }
      float pm = -INFINITY;
#pragma unroll
      for (int kt2 = 0; kt2 < 4; ++kt2)
#pragma unroll
        for (int r = 0; r < 4; ++r) pm = fmaxf(pm, St[kt2][mt][r]);
      pm = fmaxf(pm, __shfl_xor(pm, 16));
      pm = fmaxf(pm, __shfl_xor(pm, 32));
      const float mo = m_run[mt];
      const float mn = fmaxf(mo, pm);
      const float al = exp2f(mo - mn);
      m_run[mt] = mn;
      float ts = 0.f;
#pragma unroll
      for (int kt2 = 0; kt2 < 4; ++kt2) {
        float p0 = exp2f(St[kt2][mt][0] - mn);
        float p1 = exp2f(St[kt2][mt][1] - mn);
        float p2 = exp2f(St[kt2][mt][2] - mn);
        float p3 = exp2f(St[kt2][mt][3] - mn);
        ts += (p0 + p1) + (p2 + p3);
        f16x4 pk; pk[0] = (f16)p0; pk[1] = (f16)p1; pk[2] = (f16)p2; pk[3] = (f16)p3;
        int q = 16 * mt + lr;
        *reinterpret_cast<f16x4*>(
            &Ps[w][q * 64 + ((16 * kt2 + 4 * g) ^ ((q & 7) << 3))]) = pk;
      }
      ts += __shfl_xor(ts, 16);
      ts += __shfl_xor(ts, 32);
      l_run[mt] = l_run[mt] * al + ts;
#pragma unroll
      for (int dt = 0; dt < 4; ++dt)
#pragma unroll
        for (int r = 0; r < 4; ++r) Ot[mt][dt][r] *= al;
    }

    // ---- O^T += V^T · P^T ----
    __builtin_amdgcn_s_setprio(1);
#pragma unroll
    for (int kt = 0; kt < 2; ++kt) {
      f16x8 pB[2];
#pragma unroll
      for (int mt = 0; mt < 2; ++mt) {
        int q = 16 * mt + lr;
        pB[mt] = *reinterpret_cast<const f16x8*>(
            &Ps[w][q * 64 + ((32 * kt + 8 * g) ^ ((q & 7) << 3))]);
      }
#pragma unroll
      for (int dt = 0; dt < 4; ++dt) {
        int d = 16 * dt + lr;
        int s = (d + (d >> 3)) & 7;
        f16x8 vA = *reinterpret_cast<const f16x8*>(
            &Vt[cur][d * 64 + ((32 * kt + 8 * g) ^ (s << 3))]);
#pragma unroll
        for (int mt = 0; mt < 2; ++mt)
          Ot[mt][dt] = __builtin_amdgcn_mfma_f32_16x16x32_f16(
              vA, pB[mt], Ot[mt][dt], 0, 0, 0);
      }
    }
    __builtin_amdgcn_s_setprio(0);
  }

  // ---- finalize: normalize, repack via Ps, coalesced f16x8 stores ----
#pragma unroll
  for (int mt = 0; mt < 2; ++mt) {
    float inv = 1.f / l_run[mt];
    int q = 16 * mt + lr;
#pragma unroll
    for (int dt = 0; dt < 4; ++dt) {
      f16x4 ok;
#pragma unroll
      for (int r = 0; r < 4; ++r) ok[r] = (f16)(Ot[mt][dt][r] * inv);
      *reinterpret_cast<f16x4*>(
          &Ps[w][q * 64 + ((16 * dt + 4 * g) ^ ((q & 7) << 3))]) = ok;
    }
  }
  const int orow = l >> 1;
  const int ocol = (l & 1) * 32;
  const int b = bh >> 4, h = bh & (NH - 1);
#pragma unroll
  for (int i = 0; i < 4; ++i) {
    f16x8 ov = *reinterpret_cast<const f16x8*>(
        &Ps[w][orow * 64 + ((ocol + i * 8) ^ ((orow & 7) << 3))]);
    *reinterpret_cast<f16x8*>(
        &att[((size_t)(b * NT + qbase + orow)) * NC + h * HS + ocol + i * 8]) = ov;
  }
}

// ---------------------------------------------------------------------------
// Proj GEMM: att[8192,1024] f16 @ Wproj[1024,1024] fp32 + bias -> out fp32
// ---------------------------------------------------------------------------
__global__ __launch_bounds__(256) void proj_gemm(
    const f16* __restrict__ A, const float* __restrict__ W,
    const float* __restrict__ bias, float* __restrict__ Out)
{
  __shared__ __align__(16) f16 As[BM * BK];
  __shared__ __align__(16) f16 Bs[BN * BK];
  const int tid = threadIdx.x;
  const int flat = blockIdx.y * gridDim.x + blockIdx.x;   // 0..511
  const int v = (flat & 7) * 64 + (flat >> 3);
  const int m0 = (v >> 3) * BM;
  const int n0 = (v & 7) * BN;
  const int wave = tid >> 6, lane = tid & 63;
  const int wr = wave >> 1, wc = wave & 1;
  const int lr = lane & 15, hi = lane >> 4;

  f32x4 acc[4][4];
#pragma unroll
  for (int i = 0; i < 4; ++i)
#pragma unroll
    for (int j = 0; j < 4; ++j) acc[i][j] = (f32x4){0.f, 0.f, 0.f, 0.f};

  const int arow = tid >> 1, acg = (tid & 1) * 32;
  const int brow = tid >> 2, bcg = (tid & 3) * 32;

  for (int k0 = 0; k0 < NC; k0 += BK) {
    const f16* asrc = A + (size_t)(m0 + arow) * NC + k0 + acg;
#pragma unroll
    for (int i = 0; i < 4; ++i) {
      f16x8 vv = *reinterpret_cast<const f16x8*>(asrc + i * 8);
      int idx = (arow * BK + acg + i * 8) ^ ((arow & 7) << 3);
      *reinterpret_cast<f16x8*>(&As[idx]) = vv;
    }
    const float* bsrc = W + (size_t)(k0 + brow) * NC + n0 + bcg;
#pragma unroll
    for (int i = 0; i < 8; ++i) {
      float4 vv = *reinterpret_cast<const float4*>(bsrc + i * 4);
      int n = bcg + i * 4;
      Bs[((n + 0) * BK + brow) ^ bswz(n + 0)] = (f16)vv.x;
      Bs[((n + 1) * BK + brow) ^ bswz(n + 1)] = (f16)vv.y;
      Bs[((n + 2) * BK + brow) ^ bswz(n + 2)] = (f16)vv.z;
      Bs[((n + 3) * BK + brow) ^ bswz(n + 3)] = (f16)vv.w;
    }
    __syncthreads();
#pragma unroll
    for (int kk = 0; kk < BK / 32; ++kk) {
      f16x8 a[4], b[4];
#pragma unroll
      for (int mi = 0; mi < 4; ++mi) {
        int row = wr * 64 + mi * 16 + lr;
        int idx = (row * BK + kk * 32 + hi * 8) ^ ((row & 7) << 3);
        a[mi] = *reinterpret_cast<const f16x8*>(&As[idx]);
      }
#pragma unroll
      for (int ni = 0; ni < 4; ++ni) {
        int row = wc * 64 + ni * 16 + lr;
        int idx = (row * BK + kk * 32 + hi * 8) ^ bswz(row);
        b[ni] = *reinterpret_cast<const f16x8*>(&Bs[idx]);
      }
#pragma unroll
      for (int mi = 0; mi < 4; ++mi)
#pragma unroll
        for (int ni = 0; ni < 4; ++ni)
          acc[mi][ni] = __builtin_amdgcn_mfma_f32_16x16x32_f16(
              a[mi], b[ni], acc[mi][ni], 0, 0, 0);
    }
    __syncthreads();
  }

#pragma unroll
  for (int ni = 0; ni < 4; ++ni) {
    int colg = n0 + wc * 64 + ni * 16 + lr;
    float bv = bias[colg];
#pragma unroll
    for (int mi = 0; mi < 4; ++mi) {
#pragma unroll
      for (int r = 0; r < 4; ++r) {
        int rowg = m0 + wr * 64 + mi * 16 + hi * 4 + r;
        Out[(size_t)rowg * NC + colg] = acc[mi][ni][r] + bv;
      }
    }
  }
}

// ---------------------------------------------------------------------------
extern "C" void kernel_launch(void* const* d_in, const int* in_sizes, int n_in,
                              void* d_out, int out_size, void* d_ws, size_t ws_size,
                              hipStream_t stream)
{
  (void)in_sizes; (void)n_in; (void)out_size; (void)ws_size;
  const float* x     = (const float*)d_in[0];
  const float* Wqkv  = (const float*)d_in[1];
  const float* bqkv  = (const float*)d_in[2];
  const float* Wproj = (const float*)d_in[3];
  const float* bproj = (const float*)d_in[4];
  float* out = (float*)d_out;

  const size_t HE = (size_t)NB * NH * NT * HS;   // 8388608 elems per tensor
  f16* Qh  = (f16*)d_ws;
  f16* Kh  = Qh + HE;
  f16* Vh  = Kh + HE;
  f16* att = Vh + HE;

  qkv_gemm<<<dim3(3 * NC / BN, Mtot / BM), 256, 0, stream>>>(x, Wqkv, bqkv, Qh, Kh, Vh);
  flash_attn<<<dim3(NT / 256, NB * NH), 512, 0, stream>>>(Qh, Kh, Vh, att);
  proj_gemm<<<dim3(NC / BN, Mtot / BM), 256, 0, stream>>>(att, Wproj, bproj, out);
}

// Round 4
// 397.665 us; speedup vs baseline: 3.8924x; 1.3044x over previous
//
#include <hip/hip_runtime.h>

typedef _Float16 f16;
typedef _Float16 f16x4 __attribute__((ext_vector_type(4)));
typedef _Float16 f16x8 __attribute__((ext_vector_type(8)));
typedef float f32x4 __attribute__((ext_vector_type(4)));

constexpr int NB = 4, NT = 2048, NC = 1024, NH = 16, HS = 64;
constexpr int Mtot = NB * NT;            // 8192
constexpr int BM = 128, BN = 128, BK = 64;

__device__ __forceinline__ int bswz(int n) { return ((n + 2 * (n >> 5)) & 7) << 3; }

// ---------------------------------------------------------------------------
// QKV GEMM: X[8192,1024] fp32 @ W[1024,3072] fp32 + bias -> Q/K/V f16 [B,H,T,64]
// ---------------------------------------------------------------------------
__global__ __launch_bounds__(256) void qkv_gemm(
    const float* __restrict__ X, const float* __restrict__ W,
    const float* __restrict__ bias,
    f16* __restrict__ Qh, f16* __restrict__ Kh, f16* __restrict__ Vh)
{
  __shared__ __align__(16) f16 As[BM * BK];
  __shared__ __align__(16) f16 Bs[BN * BK];
  const int tid = threadIdx.x;
  const int flat = blockIdx.y * gridDim.x + blockIdx.x;        // 0..1535
  const int v = (flat & 7) * 192 + (flat >> 3);                // XCD-contig
  const int m0 = (v / 24) * BM;
  const int n0 = (v % 24) * BN;
  const int wave = tid >> 6, lane = tid & 63;
  const int wr = wave >> 1, wc = wave & 1;
  const int lr = lane & 15, hi = lane >> 4;

  f32x4 acc[4][4];
#pragma unroll
  for (int i = 0; i < 4; ++i)
#pragma unroll
    for (int j = 0; j < 4; ++j) acc[i][j] = (f32x4){0.f, 0.f, 0.f, 0.f};

  const int arow = tid >> 1, acg = (tid & 1) * 32;   // A: 2 thr/row, 32 cols each
  const int brow = tid >> 2, bcg = (tid & 3) * 32;   // B: 4 thr/k-row, 32 n each

  for (int k0 = 0; k0 < NC; k0 += BK) {
    const float* asrc = X + (size_t)(m0 + arow) * NC + k0 + acg;
#pragma unroll
    for (int i = 0; i < 8; ++i) {
      float4 vv = *reinterpret_cast<const float4*>(asrc + i * 4);
      f16x4 h; h[0] = (f16)vv.x; h[1] = (f16)vv.y; h[2] = (f16)vv.z; h[3] = (f16)vv.w;
      int idx = (arow * BK + acg + i * 4) ^ ((arow & 7) << 3);
      *reinterpret_cast<f16x4*>(&As[idx]) = h;
    }
    const float* bsrc = W + (size_t)(k0 + brow) * (3 * NC) + n0 + bcg;
#pragma unroll
    for (int i = 0; i < 8; ++i) {
      float4 vv = *reinterpret_cast<const float4*>(bsrc + i * 4);
      int n = bcg + i * 4;
      Bs[((n + 0) * BK + brow) ^ bswz(n + 0)] = (f16)vv.x;
      Bs[((n + 1) * BK + brow) ^ bswz(n + 1)] = (f16)vv.y;
      Bs[((n + 2) * BK + brow) ^ bswz(n + 2)] = (f16)vv.z;
      Bs[((n + 3) * BK + brow) ^ bswz(n + 3)] = (f16)vv.w;
    }
    __syncthreads();
#pragma unroll
    for (int kk = 0; kk < BK / 32; ++kk) {
      f16x8 a[4], b[4];
#pragma unroll
      for (int mi = 0; mi < 4; ++mi) {
        int row = wr * 64 + mi * 16 + lr;
        int idx = (row * BK + kk * 32 + hi * 8) ^ ((row & 7) << 3);
        a[mi] = *reinterpret_cast<const f16x8*>(&As[idx]);
      }
#pragma unroll
      for (int ni = 0; ni < 4; ++ni) {
        int row = wc * 64 + ni * 16 + lr;
        int idx = (row * BK + kk * 32 + hi * 8) ^ bswz(row);
        b[ni] = *reinterpret_cast<const f16x8*>(&Bs[idx]);
      }
#pragma unroll
      for (int mi = 0; mi < 4; ++mi)
#pragma unroll
        for (int ni = 0; ni < 4; ++ni)
          acc[mi][ni] = __builtin_amdgcn_mfma_f32_16x16x32_f16(
              a[mi], b[ni], acc[mi][ni], 0, 0, 0);
    }
    __syncthreads();
  }

#pragma unroll
  for (int ni = 0; ni < 4; ++ni) {
    int colg = n0 + wc * 64 + ni * 16 + lr;
    int which = colg >> 10;
    int c = colg & (NC - 1);
    int h = c >> 6, d = c & 63;
    f16* dst = (which == 0) ? Qh : ((which == 1) ? Kh : Vh);
    float bv = bias[colg];
#pragma unroll
    for (int mi = 0; mi < 4; ++mi) {
#pragma unroll
      for (int r = 0; r < 4; ++r) {
        int rowg = m0 + wr * 64 + mi * 16 + hi * 4 + r;
        int b = rowg >> 11, t = rowg & (NT - 1);
        dst[(((size_t)(b * NH + h) * NT) + t) * HS + d] =
            (f16)(acc[mi][ni][r] + bv);
      }
    }
  }
}

// ---------------------------------------------------------------------------
// MFMA flash attention, causal. Block = 8 waves x 256 q-rows, KV tile = 64,
// double-buffered K/V staging, swapped QK^T (St = K·Q^T), one barrier/tile.
// Softmax split per 16-q half-tile to keep S live-range at 16 regs.
// ---------------------------------------------------------------------------
__global__ __launch_bounds__(512, 2) void flash_attn(
    const f16* __restrict__ Qh, const f16* __restrict__ Kh,
    const f16* __restrict__ Vh, f16* __restrict__ att)
{
  __shared__ __align__(16) f16 Ks[2][64 * 64];   // [kv][d], d-swizzled by row
  __shared__ __align__(16) f16 Vt[2][64 * 64];   // [d][kv], kv-swizzled by d
  __shared__ __align__(16) f16 Ps[8][32 * 64];   // per-wave [q][kv|d], col-swizzled by q

  const int tid = threadIdx.x;
  const int w = tid >> 6, l = tid & 63;
  const int lr = l & 15, g = l >> 4;

  const int flat = blockIdx.y * gridDim.x + blockIdx.x;   // 0..511
  const int v = (flat & 7) * 64 + (flat >> 3);            // XCD-contig chunks
  const int qt = 7 - (v & 7);                             // heavy-first
  const int bh = v >> 3;

  const int qbase = qt * 256 + w * 32;
  const f16* Qb = Qh + (size_t)bh * NT * HS;
  const f16* Kb = Kh + (size_t)bh * NT * HS;
  const f16* Vb = Vh + (size_t)bh * NT * HS;

  // Q as B-operand fragments (col=lr, k=8g+j), scale (1/8)*log2(e) folded in
  f16x8 qB[2][2];
#pragma unroll
  for (int mt = 0; mt < 2; ++mt)
#pragma unroll
    for (int ds = 0; ds < 2; ++ds) {
      f16x8 t = *reinterpret_cast<const f16x8*>(
          Qb + (size_t)(qbase + 16 * mt + lr) * HS + 32 * ds + 8 * g);
#pragma unroll
      for (int j = 0; j < 8; ++j) t[j] = t[j] * (f16)0.18033688f;
      qB[mt][ds] = t;
    }

  f32x4 Ot[2][4];                       // O^T: [q-tile mt][d-tile dt], col=q=lr
  float m_run[2], l_run[2];
#pragma unroll
  for (int mt = 0; mt < 2; ++mt) {
#pragma unroll
    for (int dt = 0; dt < 4; ++dt) Ot[mt][dt] = (f32x4){0.f, 0.f, 0.f, 0.f};
    m_run[mt] = -INFINITY; l_run[mt] = 0.f;
  }

  const int srow = tid >> 3;            // 0..63
  const int scol = (tid & 7) * 8;       // 0..56
  const int jtmax = 4 * qt + 3;

  f16x8 kpre = *reinterpret_cast<const f16x8*>(Kb + (size_t)srow * HS + scol);
  f16x8 vpre = *reinterpret_cast<const f16x8*>(Vb + (size_t)srow * HS + scol);

  for (int jt = 0; jt <= jtmax; ++jt) {
    const int cur = jt & 1;
    // ---- commit prefetched tile to LDS ----
    *reinterpret_cast<f16x8*>(&Ks[cur][srow * 64 + (scol ^ ((srow & 7) << 3))]) = kpre;
#pragma unroll
    for (int j = 0; j < 8; ++j) {
      int d = scol + j;
      int s = (d + (d >> 3)) & 7;
      Vt[cur][d * 64 + (srow ^ (s << 3))] = vpre[j];
    }
    // ---- issue next tile's global loads (latency hides under compute) ----
    if (jt < jtmax) {
      kpre = *reinterpret_cast<const f16x8*>(Kb + (size_t)((jt + 1) * 64 + srow) * HS + scol);
      vpre = *reinterpret_cast<const f16x8*>(Vb + (size_t)((jt + 1) * 64 + srow) * HS + scol);
    }
    __syncthreads();

    if (jt * 64 > qbase + 31) continue;   // wave fully masked for this tile

    const bool needMask = (jt * 64 + 63) > qbase;

    // ---- per 16-q half-tile: St = K·Q^T, then online softmax ----
#pragma unroll
    for (int mt = 0; mt < 2; ++mt) {
      f32x4 St[4];                      // [kv-tile kt2], col=q=lr
#pragma unroll
      for (int kt2 = 0; kt2 < 4; ++kt2) St[kt2] = (f32x4){0.f, 0.f, 0.f, 0.f};
      __builtin_amdgcn_s_setprio(1);
#pragma unroll
      for (int kt2 = 0; kt2 < 4; ++kt2) {
        int row = 16 * kt2 + lr;
#pragma unroll
        for (int ds = 0; ds < 2; ++ds) {
          f16x8 aK = *reinterpret_cast<const f16x8*>(
              &Ks[cur][row * 64 + ((32 * ds + 8 * g) ^ ((row & 7) << 3))]);
          St[kt2] = __builtin_amdgcn_mfma_f32_16x16x32_f16(
              aK, qB[mt][ds], St[kt2], 0, 0, 0);
        }
      }
      __builtin_amdgcn_s_setprio(0);

      const int qg = qbase + 16 * mt + lr;
      if (needMask) {
#pragma unroll
        for (int kt2 = 0; kt2 < 4; ++kt2)
#pragma unroll
          for (int r = 0; r < 4; ++r)
            if ((jt * 64 + 16 * kt2 + 4 * g + r) > qg) St[kt2][r] = -INFINITY;
      }
      float pm = -INFINITY;
#pragma unroll
      for (int kt2 = 0; kt2 < 4; ++kt2)
#pragma unroll
        for (int r = 0; r < 4; ++r) pm = fmaxf(pm, St[kt2][r]);
      pm = fmaxf(pm, __shfl_xor(pm, 16));
      pm = fmaxf(pm, __shfl_xor(pm, 32));
      const float mo = m_run[mt];
      const float mn = fmaxf(mo, pm);
      const float al = exp2f(mo - mn);
      m_run[mt] = mn;
      float ts = 0.f;
      const int q = 16 * mt + lr;
#pragma unroll
      for (int kt2 = 0; kt2 < 4; ++kt2) {
        float p0 = exp2f(St[kt2][0] - mn);
        float p1 = exp2f(St[kt2][1] - mn);
        float p2 = exp2f(St[kt2][2] - mn);
        float p3 = exp2f(St[kt2][3] - mn);
        ts += (p0 + p1) + (p2 + p3);
        f16x4 pk; pk[0] = (f16)p0; pk[1] = (f16)p1; pk[2] = (f16)p2; pk[3] = (f16)p3;
        *reinterpret_cast<f16x4*>(
            &Ps[w][q * 64 + ((16 * kt2 + 4 * g) ^ ((q & 7) << 3))]) = pk;
      }
      ts += __shfl_xor(ts, 16);
      ts += __shfl_xor(ts, 32);
      l_run[mt] = l_run[mt] * al + ts;
#pragma unroll
      for (int dt = 0; dt < 4; ++dt)
#pragma unroll
        for (int r = 0; r < 4; ++r) Ot[mt][dt][r] *= al;
    }

    // ---- O^T += V^T · P^T ----
    __builtin_amdgcn_s_setprio(1);
#pragma unroll
    for (int kt = 0; kt < 2; ++kt) {
      f16x8 pB[2];
#pragma unroll
      for (int mt = 0; mt < 2; ++mt) {
        int q = 16 * mt + lr;
        pB[mt] = *reinterpret_cast<const f16x8*>(
            &Ps[w][q * 64 + ((32 * kt + 8 * g) ^ ((q & 7) << 3))]);
      }
#pragma unroll
      for (int dt = 0; dt < 4; ++dt) {
        int d = 16 * dt + lr;
        int s = (d + (d >> 3)) & 7;
        f16x8 vA = *reinterpret_cast<const f16x8*>(
            &Vt[cur][d * 64 + ((32 * kt + 8 * g) ^ (s << 3))]);
#pragma unroll
        for (int mt = 0; mt < 2; ++mt)
          Ot[mt][dt] = __builtin_amdgcn_mfma_f32_16x16x32_f16(
              vA, pB[mt], Ot[mt][dt], 0, 0, 0);
      }
    }
    __builtin_amdgcn_s_setprio(0);
  }

  // ---- finalize: normalize, repack via Ps, coalesced f16x8 stores ----
#pragma unroll
  for (int mt = 0; mt < 2; ++mt) {
    float inv = 1.f / l_run[mt];
    int q = 16 * mt + lr;
#pragma unroll
    for (int dt = 0; dt < 4; ++dt) {
      f16x4 ok;
#pragma unroll
      for (int r = 0; r < 4; ++r) ok[r] = (f16)(Ot[mt][dt][r] * inv);
      *reinterpret_cast<f16x4*>(
          &Ps[w][q * 64 + ((16 * dt + 4 * g) ^ ((q & 7) << 3))]) = ok;
    }
  }
  const int orow = l >> 1;
  const int ocol = (l & 1) * 32;
  const int b = bh >> 4, h = bh & (NH - 1);
#pragma unroll
  for (int i = 0; i < 4; ++i) {
    f16x8 ov = *reinterpret_cast<const f16x8*>(
        &Ps[w][orow * 64 + ((ocol + i * 8) ^ ((orow & 7) << 3))]);
    *reinterpret_cast<f16x8*>(
        &att[((size_t)(b * NT + qbase + orow)) * NC + h * HS + ocol + i * 8]) = ov;
  }
}

// ---------------------------------------------------------------------------
// Proj GEMM: att[8192,1024] f16 @ Wproj[1024,1024] fp32 + bias -> out fp32
// ---------------------------------------------------------------------------
__global__ __launch_bounds__(256) void proj_gemm(
    const f16* __restrict__ A, const float* __restrict__ W,
    const float* __restrict__ bias, float* __restrict__ Out)
{
  __shared__ __align__(16) f16 As[BM * BK];
  __shared__ __align__(16) f16 Bs[BN * BK];
  const int tid = threadIdx.x;
  const int flat = blockIdx.y * gridDim.x + blockIdx.x;   // 0..511
  const int v = (flat & 7) * 64 + (flat >> 3);
  const int m0 = (v >> 3) * BM;
  const int n0 = (v & 7) * BN;
  const int wave = tid >> 6, lane = tid & 63;
  const int wr = wave >> 1, wc = wave & 1;
  const int lr = lane & 15, hi = lane >> 4;

  f32x4 acc[4][4];
#pragma unroll
  for (int i = 0; i < 4; ++i)
#pragma unroll
    for (int j = 0; j < 4; ++j) acc[i][j] = (f32x4){0.f, 0.f, 0.f, 0.f};

  const int arow = tid >> 1, acg = (tid & 1) * 32;
  const int brow = tid >> 2, bcg = (tid & 3) * 32;

  for (int k0 = 0; k0 < NC; k0 += BK) {
    const f16* asrc = A + (size_t)(m0 + arow) * NC + k0 + acg;
#pragma unroll
    for (int i = 0; i < 4; ++i) {
      f16x8 vv = *reinterpret_cast<const f16x8*>(asrc + i * 8);
      int idx = (arow * BK + acg + i * 8) ^ ((arow & 7) << 3);
      *reinterpret_cast<f16x8*>(&As[idx]) = vv;
    }
    const float* bsrc = W + (size_t)(k0 + brow) * NC + n0 + bcg;
#pragma unroll
    for (int i = 0; i < 8; ++i) {
      float4 vv = *reinterpret_cast<const float4*>(bsrc + i * 4);
      int n = bcg + i * 4;
      Bs[((n + 0) * BK + brow) ^ bswz(n + 0)] = (f16)vv.x;
      Bs[((n + 1) * BK + brow) ^ bswz(n + 1)] = (f16)vv.y;
      Bs[((n + 2) * BK + brow) ^ bswz(n + 2)] = (f16)vv.z;
      Bs[((n + 3) * BK + brow) ^ bswz(n + 3)] = (f16)vv.w;
    }
    __syncthreads();
#pragma unroll
    for (int kk = 0; kk < BK / 32; ++kk) {
      f16x8 a[4], b[4];
#pragma unroll
      for (int mi = 0; mi < 4; ++mi) {
        int row = wr * 64 + mi * 16 + lr;
        int idx = (row * BK + kk * 32 + hi * 8) ^ ((row & 7) << 3);
        a[mi] = *reinterpret_cast<const f16x8*>(&As[idx]);
      }
#pragma unroll
      for (int ni = 0; ni < 4; ++ni) {
        int row = wc * 64 + ni * 16 + lr;
        int idx = (row * BK + kk * 32 + hi * 8) ^ bswz(row);
        b[ni] = *reinterpret_cast<const f16x8*>(&Bs[idx]);
      }
#pragma unroll
      for (int mi = 0; mi < 4; ++mi)
#pragma unroll
        for (int ni = 0; ni < 4; ++ni)
          acc[mi][ni] = __builtin_amdgcn_mfma_f32_16x16x32_f16(
              a[mi], b[ni], acc[mi][ni], 0, 0, 0);
    }
    __syncthreads();
  }

#pragma unroll
  for (int ni = 0; ni < 4; ++ni) {
    int colg = n0 + wc * 64 + ni * 16 + lr;
    float bv = bias[colg];
#pragma unroll
    for (int mi = 0; mi < 4; ++mi) {
#pragma unroll
      for (int r = 0; r < 4; ++r) {
        int rowg = m0 + wr * 64 + mi * 16 + hi * 4 + r;
        Out[(size_t)rowg * NC + colg] = acc[mi][ni][r] + bv;
      }
    }
  }
}

// ---------------------------------------------------------------------------
extern "C" void kernel_launch(void* const* d_in, const int* in_sizes, int n_in,
                              void* d_out, int out_size, void* d_ws, size_t ws_size,
                              hipStream_t stream)
{
  (void)in_sizes; (void)n_in; (void)out_size; (void)ws_size;
  const float* x     = (const float*)d_in[0];
  const float* Wqkv  = (const float*)d_in[1];
  const float* bqkv  = (const float*)d_in[2];
  const float* Wproj = (const float*)d_in[3];
  const float* bproj = (const float*)d_in[4];
  float* out = (float*)d_out;

  const size_t HE = (size_t)NB * NH * NT * HS;   // 8388608 elems per tensor
  f16* Qh  = (f16*)d_ws;
  f16* Kh  = Qh + HE;
  f16* Vh  = Kh + HE;
  f16* att = Vh + HE;

  qkv_gemm<<<dim3(3 * NC / BN, Mtot / BM), 256, 0, stream>>>(x, Wqkv, bqkv, Qh, Kh, Vh);
  flash_attn<<<dim3(NT / 256, NB * NH), 512, 0, stream>>>(Qh, Kh, Vh, att);
  proj_gemm<<<dim3(NC / BN, Mtot / BM), 256, 0, stream>>>(att, Wproj, bproj, out);
}

// Round 5
// 250.162 us; speedup vs baseline: 6.1875x; 1.5896x over previous
//
#include <hip/hip_runtime.h>
#include <cstdint>

typedef _Float16 f16;
typedef _Float16 f16x4 __attribute__((ext_vector_type(4)));
typedef _Float16 f16x8 __attribute__((ext_vector_type(8)));
typedef float f32x4 __attribute__((ext_vector_type(4)));

constexpr int NB = 4, NT = 2048, NC = 1024, NH = 16, HS = 64;
constexpr int Mtot = NB * NT;            // 8192
constexpr int BM = 128, BN = 128;

// async global->LDS 16B (CK-style addrspace casts)
__device__ __forceinline__ void gll16(const f16* g, f16* l) {
  __builtin_amdgcn_global_load_lds(
      (const __attribute__((address_space(1))) unsigned int*)(uintptr_t)g,
      (__attribute__((address_space(3))) unsigned int*)(uintptr_t)l, 16, 0, 0);
}

// ---------------------------------------------------------------------------
// X fp32 -> f16 (same layout)
// ---------------------------------------------------------------------------
__global__ __launch_bounds__(256) void convert_x(
    const float* __restrict__ X, f16* __restrict__ Xh)
{
  const size_t i = ((size_t)blockIdx.x * 256 + threadIdx.x) * 8;
  float4 a = *reinterpret_cast<const float4*>(X + i);
  float4 b = *reinterpret_cast<const float4*>(X + i + 4);
  f16x8 o;
  o[0] = (f16)a.x; o[1] = (f16)a.y; o[2] = (f16)a.z; o[3] = (f16)a.w;
  o[4] = (f16)b.x; o[5] = (f16)b.y; o[6] = (f16)b.z; o[7] = (f16)b.w;
  *reinterpret_cast<f16x8*>(Xh + i) = o;
}

// ---------------------------------------------------------------------------
// W_qkv [1024][3072] & W_proj [1024][1024] fp32 -> transposed f16 [n][k]
// ---------------------------------------------------------------------------
__global__ __launch_bounds__(256) void transpose_w(
    const float* __restrict__ Wq, const float* __restrict__ Wp,
    f16* __restrict__ Wqt, f16* __restrict__ Wpt)
{
  __shared__ __align__(16) f16 Ts[64 * 72];
  const int bx = blockIdx.x;
  const float* src; f16* dst; int Ndim, n0;
  if (bx < 48) { src = Wq; dst = Wqt; Ndim = 3 * NC; n0 = bx * 64; }
  else         { src = Wp; dst = Wpt; Ndim = NC;     n0 = (bx - 48) * 64; }
  const int k0 = blockIdx.y * 64;
  const int t = threadIdx.x;
  const int kl = t >> 2, nb = (t & 3) * 16;
#pragma unroll
  for (int i = 0; i < 4; ++i) {
    float4 vv = *reinterpret_cast<const float4*>(
        src + (size_t)(k0 + kl) * Ndim + n0 + nb + 4 * i);
    f16x4 h; h[0] = (f16)vv.x; h[1] = (f16)vv.y; h[2] = (f16)vv.z; h[3] = (f16)vv.w;
    *reinterpret_cast<f16x4*>(&Ts[kl * 72 + nb + 4 * i]) = h;
  }
  __syncthreads();
  const int nl = t >> 2, kb = (t & 3) * 16;
#pragma unroll
  for (int i = 0; i < 2; ++i) {
    f16x8 o;
#pragma unroll
    for (int j = 0; j < 8; ++j) o[j] = Ts[(kb + 8 * i + j) * 72 + nl];
    *reinterpret_cast<f16x8*>(dst + (size_t)(n0 + nl) * NC + k0 + kb + 8 * i) = o;
  }
}

// ---------------------------------------------------------------------------
// f16 GEMM, 128x128 tile, BK=64, global_load_lds staging (pre-swizzled src).
// A[M][1024] row-major, Bt[N][1024] row-major.
// MODE 0: qkv epilogue (bias + head split -> Q/K/V f16)
// MODE 1: proj epilogue (bias -> fp32 out)
// ---------------------------------------------------------------------------
template <int MODE>
__global__ __launch_bounds__(256) void gemm_f16(
    const f16* __restrict__ A, const f16* __restrict__ Bt,
    const float* __restrict__ bias,
    f16* __restrict__ Qh, f16* __restrict__ Kh, f16* __restrict__ Vh,
    float* __restrict__ Out, int ntiles)
{
  __shared__ __align__(16) f16 As[BM * 64];
  __shared__ __align__(16) f16 Bs[BN * 64];
  const int tid = threadIdx.x;
  const int flat = blockIdx.x;
  const int cpx = gridDim.x >> 3;
  const int v = (flat & 7) * cpx + (flat >> 3);       // XCD-contig chunks
  const int m0 = (v / ntiles) * BM;
  const int n0 = (v % ntiles) * BN;
  const int w = tid >> 6, l = tid & 63;
  const int wr = w >> 1, wc = w & 1;
  const int lr = l & 15, hi = l >> 4;

  f32x4 acc[4][4];
#pragma unroll
  for (int i = 0; i < 4; ++i)
#pragma unroll
    for (int j = 0; j < 4; ++j) acc[i][j] = (f32x4){0.f, 0.f, 0.f, 0.f};

  const int lrow = l >> 3;                  // 0..7 relative row within 8-row burst
  const int lsrc = ((l & 7) ^ lrow) * 8;    // inverse-swizzled k-offset (f16 units)

  for (int k0 = 0; k0 < NC; k0 += 64) {
    __syncthreads();                        // prior compute done reading LDS
#pragma unroll
    for (int i = 0; i < 4; ++i) {
      const int rr = 32 * w + 8 * i;        // rr % 8 == 0, so row&7 == lrow
      gll16(A  + (size_t)(m0 + rr + lrow) * NC + k0 + lsrc, &As[rr * 64]);
      gll16(Bt + (size_t)(n0 + rr + lrow) * NC + k0 + lsrc, &Bs[rr * 64]);
    }
    __syncthreads();                        // drains vmcnt(0): tiles ready
#pragma unroll
    for (int kk = 0; kk < 2; ++kk) {
      f16x8 a[4], b[4];
#pragma unroll
      for (int mi = 0; mi < 4; ++mi) {
        int row = wr * 64 + mi * 16 + lr;
        int idx = (row * 64 + kk * 32 + hi * 8) ^ ((row & 7) << 3);
        a[mi] = *reinterpret_cast<const f16x8*>(&As[idx]);
      }
#pragma unroll
      for (int ni = 0; ni < 4; ++ni) {
        int row = wc * 64 + ni * 16 + lr;
        int idx = (row * 64 + kk * 32 + hi * 8) ^ ((row & 7) << 3);
        b[ni] = *reinterpret_cast<const f16x8*>(&Bs[idx]);
      }
#pragma unroll
      for (int mi = 0; mi < 4; ++mi)
#pragma unroll
        for (int ni = 0; ni < 4; ++ni)
          acc[mi][ni] = __builtin_amdgcn_mfma_f32_16x16x32_f16(
              a[mi], b[ni], acc[mi][ni], 0, 0, 0);
    }
  }

  if (MODE == 0) {
#pragma unroll
    for (int ni = 0; ni < 4; ++ni) {
      int colg = n0 + wc * 64 + ni * 16 + lr;
      int which = colg >> 10;
      int c = colg & (NC - 1);
      int h = c >> 6, d = c & 63;
      f16* dst = (which == 0) ? Qh : ((which == 1) ? Kh : Vh);
      float bv = bias[colg];
#pragma unroll
      for (int mi = 0; mi < 4; ++mi) {
#pragma unroll
        for (int r = 0; r < 4; ++r) {
          int rowg = m0 + wr * 64 + mi * 16 + hi * 4 + r;
          int b = rowg >> 11, t = rowg & (NT - 1);
          dst[(((size_t)(b * NH + h) * NT) + t) * HS + d] =
              (f16)(acc[mi][ni][r] + bv);
        }
      }
    }
  } else {
#pragma unroll
    for (int ni = 0; ni < 4; ++ni) {
      int colg = n0 + wc * 64 + ni * 16 + lr;
      float bv = bias[colg];
#pragma unroll
      for (int mi = 0; mi < 4; ++mi) {
#pragma unroll
        for (int r = 0; r < 4; ++r) {
          int rowg = m0 + wr * 64 + mi * 16 + hi * 4 + r;
          Out[(size_t)rowg * NC + colg] = acc[mi][ni][r] + bv;
        }
      }
    }
  }
}

// ---------------------------------------------------------------------------
// MFMA flash attention, causal. Block = 8 waves x 256 q-rows, KV tile = 64,
// double-buffered K/V staging, swapped QK^T (St = K·Q^T), one barrier/tile.
// ---------------------------------------------------------------------------
__global__ __launch_bounds__(512, 2) void flash_attn(
    const f16* __restrict__ Qh, const f16* __restrict__ Kh,
    const f16* __restrict__ Vh, f16* __restrict__ att)
{
  __shared__ __align__(16) f16 Ks[2][64 * 64];   // [kv][d], d-swizzled by row
  __shared__ __align__(16) f16 Vt[2][64 * 64];   // [d][kv], kv-swizzled by d
  __shared__ __align__(16) f16 Ps[8][32 * 64];   // per-wave [q][kv|d], col-swizzled by q

  const int tid = threadIdx.x;
  const int w = tid >> 6, l = tid & 63;
  const int lr = l & 15, g = l >> 4;

  const int flat = blockIdx.y * gridDim.x + blockIdx.x;   // 0..511
  const int v = (flat & 7) * 64 + (flat >> 3);            // XCD-contig chunks
  const int qt = 7 - (v & 7);                             // heavy-first
  const int bh = v >> 3;

  const int qbase = qt * 256 + w * 32;
  const f16* Qb = Qh + (size_t)bh * NT * HS;
  const f16* Kb = Kh + (size_t)bh * NT * HS;
  const f16* Vb = Vh + (size_t)bh * NT * HS;

  // Q as B-operand fragments (col=lr, k=8g+j), scale (1/8)*log2(e) folded in
  f16x8 qB[2][2];
#pragma unroll
  for (int mt = 0; mt < 2; ++mt)
#pragma unroll
    for (int ds = 0; ds < 2; ++ds) {
      f16x8 t = *reinterpret_cast<const f16x8*>(
          Qb + (size_t)(qbase + 16 * mt + lr) * HS + 32 * ds + 8 * g);
#pragma unroll
      for (int j = 0; j < 8; ++j) t[j] = t[j] * (f16)0.18033688f;
      qB[mt][ds] = t;
    }

  f32x4 Ot[2][4];                       // O^T: [q-tile mt][d-tile dt], col=q=lr
  float m_run[2], l_run[2];
#pragma unroll
  for (int mt = 0; mt < 2; ++mt) {
#pragma unroll
    for (int dt = 0; dt < 4; ++dt) Ot[mt][dt] = (f32x4){0.f, 0.f, 0.f, 0.f};
    m_run[mt] = -INFINITY; l_run[mt] = 0.f;
  }

  const int srow = tid >> 3;            // 0..63
  const int scol = (tid & 7) * 8;       // 0..56
  const int jtmax = 4 * qt + 3;

  f16x8 kpre = *reinterpret_cast<const f16x8*>(Kb + (size_t)srow * HS + scol);
  f16x8 vpre = *reinterpret_cast<const f16x8*>(Vb + (size_t)srow * HS + scol);

  for (int jt = 0; jt <= jtmax; ++jt) {
    const int cur = jt & 1;
    // ---- commit prefetched tile to LDS ----
    *reinterpret_cast<f16x8*>(&Ks[cur][srow * 64 + (scol ^ ((srow & 7) << 3))]) = kpre;
#pragma unroll
    for (int j = 0; j < 8; ++j) {
      int d = scol + j;
      int s = (d + (d >> 3)) & 7;
      Vt[cur][d * 64 + (srow ^ (s << 3))] = vpre[j];
    }
    // ---- issue next tile's global loads (latency hides under compute) ----
    if (jt < jtmax) {
      kpre = *reinterpret_cast<const f16x8*>(Kb + (size_t)((jt + 1) * 64 + srow) * HS + scol);
      vpre = *reinterpret_cast<const f16x8*>(Vb + (size_t)((jt + 1) * 64 + srow) * HS + scol);
    }
    __syncthreads();

    if (jt * 64 > qbase + 31) continue;   // wave fully masked for this tile

    const bool needMask = (jt * 64 + 63) > qbase;

    // ---- per 16-q half-tile: St = K·Q^T, then online softmax ----
#pragma unroll
    for (int mt = 0; mt < 2; ++mt) {
      f32x4 St[4];                      // [kv-tile kt2], col=q=lr
#pragma unroll
      for (int kt2 = 0; kt2 < 4; ++kt2) St[kt2] = (f32x4){0.f, 0.f, 0.f, 0.f};
      __builtin_amdgcn_s_setprio(1);
#pragma unroll
      for (int kt2 = 0; kt2 < 4; ++kt2) {
        int row = 16 * kt2 + lr;
#pragma unroll
        for (int ds = 0; ds < 2; ++ds) {
          f16x8 aK = *reinterpret_cast<const f16x8*>(
              &Ks[cur][row * 64 + ((32 * ds + 8 * g) ^ ((row & 7) << 3))]);
          St[kt2] = __builtin_amdgcn_mfma_f32_16x16x32_f16(
              aK, qB[mt][ds], St[kt2], 0, 0, 0);
        }
      }
      __builtin_amdgcn_s_setprio(0);

      const int qg = qbase + 16 * mt + lr;
      if (needMask) {
#pragma unroll
        for (int kt2 = 0; kt2 < 4; ++kt2)
#pragma unroll
          for (int r = 0; r < 4; ++r)
            if ((jt * 64 + 16 * kt2 + 4 * g + r) > qg) St[kt2][r] = -INFINITY;
      }
      float pm = -INFINITY;
#pragma unroll
      for (int kt2 = 0; kt2 < 4; ++kt2)
#pragma unroll
        for (int r = 0; r < 4; ++r) pm = fmaxf(pm, St[kt2][r]);
      pm = fmaxf(pm, __shfl_xor(pm, 16));
      pm = fmaxf(pm, __shfl_xor(pm, 32));
      const float mo = m_run[mt];
      const float mn = fmaxf(mo, pm);
      const float al = exp2f(mo - mn);
      m_run[mt] = mn;
      float ts = 0.f;
      const int q = 16 * mt + lr;
#pragma unroll
      for (int kt2 = 0; kt2 < 4; ++kt2) {
        float p0 = exp2f(St[kt2][0] - mn);
        float p1 = exp2f(St[kt2][1] - mn);
        float p2 = exp2f(St[kt2][2] - mn);
        float p3 = exp2f(St[kt2][3] - mn);
        ts += (p0 + p1) + (p2 + p3);
        f16x4 pk; pk[0] = (f16)p0; pk[1] = (f16)p1; pk[2] = (f16)p2; pk[3] = (f16)p3;
        *reinterpret_cast<f16x4*>(
            &Ps[w][q * 64 + ((16 * kt2 + 4 * g) ^ ((q & 7) << 3))]) = pk;
      }
      ts += __shfl_xor(ts, 16);
      ts += __shfl_xor(ts, 32);
      l_run[mt] = l_run[mt] * al + ts;
#pragma unroll
      for (int dt = 0; dt < 4; ++dt)
#pragma unroll
        for (int r = 0; r < 4; ++r) Ot[mt][dt][r] *= al;
    }

    // ---- O^T += V^T · P^T ----
    __builtin_amdgcn_s_setprio(1);
#pragma unroll
    for (int kt = 0; kt < 2; ++kt) {
      f16x8 pB[2];
#pragma unroll
      for (int mt = 0; mt < 2; ++mt) {
        int q = 16 * mt + lr;
        pB[mt] = *reinterpret_cast<const f16x8*>(
            &Ps[w][q * 64 + ((32 * kt + 8 * g) ^ ((q & 7) << 3))]);
      }
#pragma unroll
      for (int dt = 0; dt < 4; ++dt) {
        int d = 16 * dt + lr;
        int s = (d + (d >> 3)) & 7;
        f16x8 vA = *reinterpret_cast<const f16x8*>(
            &Vt[cur][d * 64 + ((32 * kt + 8 * g) ^ (s << 3))]);
#pragma unroll
        for (int mt = 0; mt < 2; ++mt)
          Ot[mt][dt] = __builtin_amdgcn_mfma_f32_16x16x32_f16(
              vA, pB[mt], Ot[mt][dt], 0, 0, 0);
      }
    }
    __builtin_amdgcn_s_setprio(0);
  }

  // ---- finalize: normalize, repack via Ps, coalesced f16x8 stores ----
#pragma unroll
  for (int mt = 0; mt < 2; ++mt) {
    float inv = 1.f / l_run[mt];
    int q = 16 * mt + lr;
#pragma unroll
    for (int dt = 0; dt < 4; ++dt) {
      f16x4 ok;
#pragma unroll
      for (int r = 0; r < 4; ++r) ok[r] = (f16)(Ot[mt][dt][r] * inv);
      *reinterpret_cast<f16x4*>(
          &Ps[w][q * 64 + ((16 * dt + 4 * g) ^ ((q & 7) << 3))]) = ok;
    }
  }
  const int orow = l >> 1;
  const int ocol = (l & 1) * 32;
  const int b = bh >> 4, h = bh & (NH - 1);
#pragma unroll
  for (int i = 0; i < 4; ++i) {
    f16x8 ov = *reinterpret_cast<const f16x8*>(
        &Ps[w][orow * 64 + ((ocol + i * 8) ^ ((orow & 7) << 3))]);
    *reinterpret_cast<f16x8*>(
        &att[((size_t)(b * NT + qbase + orow)) * NC + h * HS + ocol + i * 8]) = ov;
  }
}

// ---------------------------------------------------------------------------
extern "C" void kernel_launch(void* const* d_in, const int* in_sizes, int n_in,
                              void* d_out, int out_size, void* d_ws, size_t ws_size,
                              hipStream_t stream)
{
  (void)in_sizes; (void)n_in; (void)out_size; (void)ws_size;
  const float* x     = (const float*)d_in[0];
  const float* Wqkv  = (const float*)d_in[1];
  const float* bqkv  = (const float*)d_in[2];
  const float* Wproj = (const float*)d_in[3];
  const float* bproj = (const float*)d_in[4];
  float* out = (float*)d_out;

  const size_t HE = (size_t)NB * NH * NT * HS;   // 8388608 elems per tensor
  f16* Qh  = (f16*)d_ws;
  f16* Kh  = Qh + HE;
  f16* Vh  = Kh + HE;
  f16* XA  = Vh + HE;            // Xh (pre-attn) aliases att (post-attn)
  f16* Wqt = XA + HE;            // 3072x1024
  f16* Wpt = Wqt + (size_t)3 * NC * NC;  // 1024x1024

  convert_x<<<dim3(Mtot * NC / (256 * 8)), 256, 0, stream>>>(x, XA);
  transpose_w<<<dim3(64, 16), 256, 0, stream>>>(Wqkv, Wproj, Wqt, Wpt);
  gemm_f16<0><<<dim3(64 * 24), 256, 0, stream>>>(XA, Wqt, bqkv, Qh, Kh, Vh, nullptr, 24);
  flash_attn<<<dim3(NT / 256, NB * NH), 512, 0, stream>>>(Qh, Kh, Vh, XA);
  gemm_f16<1><<<dim3(64 * 8), 256, 0, stream>>>(XA, Wpt, bproj, nullptr, nullptr, nullptr, out, 8);
}

// Round 6
// 191.478 us; speedup vs baseline: 8.0839x; 1.3065x over previous
//
#include <hip/hip_runtime.h>
#include <cstdint>

typedef _Float16 f16;
typedef _Float16 f16x4 __attribute__((ext_vector_type(4)));
typedef _Float16 f16x8 __attribute__((ext_vector_type(8)));
typedef float f32x4 __attribute__((ext_vector_type(4)));

constexpr int NB = 4, NT = 2048, NC = 1024, NH = 16, HS = 64;
constexpr int Mtot = NB * NT;            // 8192
constexpr int BM = 128, BN = 128;

// async global->LDS 16B (CK-style addrspace casts)
__device__ __forceinline__ void gll16(const f16* g, f16* l) {
  __builtin_amdgcn_global_load_lds(
      (const __attribute__((address_space(1))) unsigned int*)(uintptr_t)g,
      (__attribute__((address_space(3))) unsigned int*)(uintptr_t)l, 16, 0, 0);
}

// ---------------------------------------------------------------------------
// X fp32 -> f16 (same layout)
// ---------------------------------------------------------------------------
__global__ __launch_bounds__(256) void convert_x(
    const float* __restrict__ X, f16* __restrict__ Xh)
{
  const size_t i = ((size_t)blockIdx.x * 256 + threadIdx.x) * 8;
  float4 a = *reinterpret_cast<const float4*>(X + i);
  float4 b = *reinterpret_cast<const float4*>(X + i + 4);
  f16x8 o;
  o[0] = (f16)a.x; o[1] = (f16)a.y; o[2] = (f16)a.z; o[3] = (f16)a.w;
  o[4] = (f16)b.x; o[5] = (f16)b.y; o[6] = (f16)b.z; o[7] = (f16)b.w;
  *reinterpret_cast<f16x8*>(Xh + i) = o;
}

// ---------------------------------------------------------------------------
// W_qkv [1024][3072] & W_proj [1024][1024] fp32 -> transposed f16 [n][k]
// ---------------------------------------------------------------------------
__global__ __launch_bounds__(256) void transpose_w(
    const float* __restrict__ Wq, const float* __restrict__ Wp,
    f16* __restrict__ Wqt, f16* __restrict__ Wpt)
{
  __shared__ __align__(16) f16 Ts[64 * 72];
  const int bx = blockIdx.x;
  const float* src; f16* dst; int Ndim, n0;
  if (bx < 48) { src = Wq; dst = Wqt; Ndim = 3 * NC; n0 = bx * 64; }
  else         { src = Wp; dst = Wpt; Ndim = NC;     n0 = (bx - 48) * 64; }
  const int k0 = blockIdx.y * 64;
  const int t = threadIdx.x;
  const int kl = t >> 2, nb = (t & 3) * 16;
#pragma unroll
  for (int i = 0; i < 4; ++i) {
    float4 vv = *reinterpret_cast<const float4*>(
        src + (size_t)(k0 + kl) * Ndim + n0 + nb + 4 * i);
    f16x4 h; h[0] = (f16)vv.x; h[1] = (f16)vv.y; h[2] = (f16)vv.z; h[3] = (f16)vv.w;
    *reinterpret_cast<f16x4*>(&Ts[kl * 72 + nb + 4 * i]) = h;
  }
  __syncthreads();
  const int nl = t >> 2, kb = (t & 3) * 16;
#pragma unroll
  for (int i = 0; i < 2; ++i) {
    f16x8 o;
#pragma unroll
    for (int j = 0; j < 8; ++j) o[j] = Ts[(kb + 8 * i + j) * 72 + nl];
    *reinterpret_cast<f16x8*>(dst + (size_t)(n0 + nl) * NC + k0 + kb + 8 * i) = o;
  }
}

// ---------------------------------------------------------------------------
// f16 GEMM, 128x128 tile, BK=64, global_load_lds staging (pre-swizzled src).
// ---------------------------------------------------------------------------
template <int MODE>
__global__ __launch_bounds__(256) void gemm_f16(
    const f16* __restrict__ A, const f16* __restrict__ Bt,
    const float* __restrict__ bias,
    f16* __restrict__ Qh, f16* __restrict__ Kh, f16* __restrict__ Vh,
    float* __restrict__ Out, int ntiles)
{
  __shared__ __align__(16) f16 As[BM * 64];
  __shared__ __align__(16) f16 Bs[BN * 64];
  const int tid = threadIdx.x;
  const int flat = blockIdx.x;
  const int cpx = gridDim.x >> 3;
  const int v = (flat & 7) * cpx + (flat >> 3);       // XCD-contig chunks
  const int m0 = (v / ntiles) * BM;
  const int n0 = (v % ntiles) * BN;
  const int w = tid >> 6, l = tid & 63;
  const int wr = w >> 1, wc = w & 1;
  const int lr = l & 15, hi = l >> 4;

  f32x4 acc[4][4];
#pragma unroll
  for (int i = 0; i < 4; ++i)
#pragma unroll
    for (int j = 0; j < 4; ++j) acc[i][j] = (f32x4){0.f, 0.f, 0.f, 0.f};

  const int lrow = l >> 3;
  const int lsrc = ((l & 7) ^ lrow) * 8;

  for (int k0 = 0; k0 < NC; k0 += 64) {
    __syncthreads();
#pragma unroll
    for (int i = 0; i < 4; ++i) {
      const int rr = 32 * w + 8 * i;
      gll16(A  + (size_t)(m0 + rr + lrow) * NC + k0 + lsrc, &As[rr * 64]);
      gll16(Bt + (size_t)(n0 + rr + lrow) * NC + k0 + lsrc, &Bs[rr * 64]);
    }
    __syncthreads();
#pragma unroll
    for (int kk = 0; kk < 2; ++kk) {
      f16x8 a[4], b[4];
#pragma unroll
      for (int mi = 0; mi < 4; ++mi) {
        int row = wr * 64 + mi * 16 + lr;
        int idx = (row * 64 + kk * 32 + hi * 8) ^ ((row & 7) << 3);
        a[mi] = *reinterpret_cast<const f16x8*>(&As[idx]);
      }
#pragma unroll
      for (int ni = 0; ni < 4; ++ni) {
        int row = wc * 64 + ni * 16 + lr;
        int idx = (row * 64 + kk * 32 + hi * 8) ^ ((row & 7) << 3);
        b[ni] = *reinterpret_cast<const f16x8*>(&Bs[idx]);
      }
#pragma unroll
      for (int mi = 0; mi < 4; ++mi)
#pragma unroll
        for (int ni = 0; ni < 4; ++ni)
          acc[mi][ni] = __builtin_amdgcn_mfma_f32_16x16x32_f16(
              a[mi], b[ni], acc[mi][ni], 0, 0, 0);
    }
  }

  if (MODE == 0) {
#pragma unroll
    for (int ni = 0; ni < 4; ++ni) {
      int colg = n0 + wc * 64 + ni * 16 + lr;
      int which = colg >> 10;
      int c = colg & (NC - 1);
      int h = c >> 6, d = c & 63;
      f16* dst = (which == 0) ? Qh : ((which == 1) ? Kh : Vh);
      float bv = bias[colg];
#pragma unroll
      for (int mi = 0; mi < 4; ++mi) {
#pragma unroll
        for (int r = 0; r < 4; ++r) {
          int rowg = m0 + wr * 64 + mi * 16 + hi * 4 + r;
          int b = rowg >> 11, t = rowg & (NT - 1);
          dst[(((size_t)(b * NH + h) * NT) + t) * HS + d] =
              (f16)(acc[mi][ni][r] + bv);
        }
      }
    }
  } else {
#pragma unroll
    for (int ni = 0; ni < 4; ++ni) {
      int colg = n0 + wc * 64 + ni * 16 + lr;
      float bv = bias[colg];
#pragma unroll
      for (int mi = 0; mi < 4; ++mi) {
#pragma unroll
        for (int r = 0; r < 4; ++r) {
          int rowg = m0 + wr * 64 + mi * 16 + hi * 4 + r;
          Out[(size_t)rowg * NC + colg] = acc[mi][ni][r] + bv;
        }
      }
    }
  }
}

// ---------------------------------------------------------------------------
// MFMA flash attention, causal. Block = 4 waves x 128 q-rows; each block does
// the q-tile pair {qt, 15-qt} -> uniform 34 kv-tiles/block. KV tile = 64,
// double-buffered, swapped QK^T (St = K·Q^T), one barrier per tile,
// K-fragments cached in registers across the mt softmax split.
// ---------------------------------------------------------------------------
__global__ __launch_bounds__(256, 2) void flash_attn(
    const f16* __restrict__ Qh, const f16* __restrict__ Kh,
    const f16* __restrict__ Vh, f16* __restrict__ att)
{
  __shared__ __align__(16) f16 Ks[2][64 * 64];   // [kv][d], d-swizzled by row
  __shared__ __align__(16) f16 Vt[2][64 * 64];   // [d][kv], kv-swizzled by d
  __shared__ __align__(16) f16 Ps[4][32 * 64];   // per-wave staging

  const int tid = threadIdx.x;
  const int w = tid >> 6, l = tid & 63;
  const int lr = l & 15, g = l >> 4;

  const int flat = blockIdx.x;                    // 0..511
  const int v = (flat & 7) * 64 + (flat >> 3);    // XCD-contig chunks
  const int pairi = v & 7;                        // 0..7
  const int bh = v >> 3;                          // 0..63

  const f16* Qb = Qh + (size_t)bh * NT * HS;
  const f16* Kb = Kh + (size_t)bh * NT * HS;
  const f16* Vb = Vh + (size_t)bh * NT * HS;
  const int ob = bh >> 4, oh = bh & (NH - 1);

  const int srow = tid >> 2;            // 0..63
  const int scol = (tid & 3) * 16;      // 0,16,32,48

  f16x8 kpre[2], vpre[2];
#pragma unroll
  for (int ii = 0; ii < 2; ++ii) {
    kpre[ii] = *reinterpret_cast<const f16x8*>(Kb + (size_t)srow * HS + scol + 8 * ii);
    vpre[ii] = *reinterpret_cast<const f16x8*>(Vb + (size_t)srow * HS + scol + 8 * ii);
  }

  for (int seg = 0; seg < 2; ++seg) {
    const int qt = (seg == 0) ? pairi : 15 - pairi;
    const int qbase = qt * 128 + w * 32;
    const int jtmax = 2 * qt + 1;

    // Q as B-operand fragments (col=lr, k=8g+j), scale (1/8)*log2(e) folded
    f16x8 qB[2][2];
#pragma unroll
    for (int mt = 0; mt < 2; ++mt)
#pragma unroll
      for (int ds = 0; ds < 2; ++ds) {
        f16x8 t = *reinterpret_cast<const f16x8*>(
            Qb + (size_t)(qbase + 16 * mt + lr) * HS + 32 * ds + 8 * g);
#pragma unroll
        for (int j = 0; j < 8; ++j) t[j] = t[j] * (f16)0.18033688f;
        qB[mt][ds] = t;
      }

    f32x4 Ot[2][4];
    float m_run[2], l_run[2];
#pragma unroll
    for (int mt = 0; mt < 2; ++mt) {
#pragma unroll
      for (int dt = 0; dt < 4; ++dt) Ot[mt][dt] = (f32x4){0.f, 0.f, 0.f, 0.f};
      m_run[mt] = -INFINITY; l_run[mt] = 0.f;
    }

    for (int jt = 0; jt <= jtmax; ++jt) {
      const int cur = jt & 1;
      // ---- commit prefetched tile to LDS ----
#pragma unroll
      for (int ii = 0; ii < 2; ++ii) {
        int c0 = scol + 8 * ii;
        *reinterpret_cast<f16x8*>(&Ks[cur][srow * 64 + (c0 ^ ((srow & 7) << 3))]) = kpre[ii];
#pragma unroll
        for (int j = 0; j < 8; ++j) {
          int d = c0 + j;
          int s = (d + (d >> 3)) & 7;
          Vt[cur][d * 64 + (srow ^ (s << 3))] = vpre[ii][j];
        }
      }
      // ---- issue next tile's global loads ----
      const bool more = (jt < jtmax) || (seg == 0);
      if (more) {
        const int nj = (jt < jtmax) ? jt + 1 : 0;
#pragma unroll
        for (int ii = 0; ii < 2; ++ii) {
          kpre[ii] = *reinterpret_cast<const f16x8*>(
              Kb + (size_t)(nj * 64 + srow) * HS + scol + 8 * ii);
          vpre[ii] = *reinterpret_cast<const f16x8*>(
              Vb + (size_t)(nj * 64 + srow) * HS + scol + 8 * ii);
        }
      }
      __syncthreads();

      if (jt * 64 > qbase + 31) continue;   // wave fully masked for this tile

      const bool needMask = (jt * 64 + 63) > qbase;

      // ---- cache K fragments (A-operand) in registers, once per tile ----
      f16x8 aK[4][2];
#pragma unroll
      for (int kt2 = 0; kt2 < 4; ++kt2) {
        int row = 16 * kt2 + lr;
#pragma unroll
        for (int ds = 0; ds < 2; ++ds)
          aK[kt2][ds] = *reinterpret_cast<const f16x8*>(
              &Ks[cur][row * 64 + ((32 * ds + 8 * g) ^ ((row & 7) << 3))]);
      }

      // ---- per 16-q half-tile: St = K·Q^T, then online softmax ----
#pragma unroll
      for (int mt = 0; mt < 2; ++mt) {
        f32x4 St[4];
#pragma unroll
        for (int kt2 = 0; kt2 < 4; ++kt2) St[kt2] = (f32x4){0.f, 0.f, 0.f, 0.f};
        __builtin_amdgcn_s_setprio(1);
#pragma unroll
        for (int kt2 = 0; kt2 < 4; ++kt2)
#pragma unroll
          for (int ds = 0; ds < 2; ++ds)
            St[kt2] = __builtin_amdgcn_mfma_f32_16x16x32_f16(
                aK[kt2][ds], qB[mt][ds], St[kt2], 0, 0, 0);
        __builtin_amdgcn_s_setprio(0);

        const int qg = qbase + 16 * mt + lr;
        if (needMask) {
#pragma unroll
          for (int kt2 = 0; kt2 < 4; ++kt2)
#pragma unroll
            for (int r = 0; r < 4; ++r)
              if ((jt * 64 + 16 * kt2 + 4 * g + r) > qg) St[kt2][r] = -INFINITY;
        }
        float pm = -INFINITY;
#pragma unroll
        for (int kt2 = 0; kt2 < 4; ++kt2)
#pragma unroll
          for (int r = 0; r < 4; ++r) pm = fmaxf(pm, St[kt2][r]);
        pm = fmaxf(pm, __shfl_xor(pm, 16));
        pm = fmaxf(pm, __shfl_xor(pm, 32));
        const float mo = m_run[mt];
        const float mn = fmaxf(mo, pm);
        const float al = exp2f(mo - mn);
        m_run[mt] = mn;
        float ts = 0.f;
        const int q = 16 * mt + lr;
#pragma unroll
        for (int kt2 = 0; kt2 < 4; ++kt2) {
          float p0 = exp2f(St[kt2][0] - mn);
          float p1 = exp2f(St[kt2][1] - mn);
          float p2 = exp2f(St[kt2][2] - mn);
          float p3 = exp2f(St[kt2][3] - mn);
          ts += (p0 + p1) + (p2 + p3);
          f16x4 pk; pk[0] = (f16)p0; pk[1] = (f16)p1; pk[2] = (f16)p2; pk[3] = (f16)p3;
          *reinterpret_cast<f16x4*>(
              &Ps[w][q * 64 + ((16 * kt2 + 4 * g) ^ ((q & 7) << 3))]) = pk;
        }
        ts += __shfl_xor(ts, 16);
        ts += __shfl_xor(ts, 32);
        l_run[mt] = l_run[mt] * al + ts;
#pragma unroll
        for (int dt = 0; dt < 4; ++dt)
#pragma unroll
          for (int r = 0; r < 4; ++r) Ot[mt][dt][r] *= al;
      }

      // ---- O^T += V^T · P^T ----
      __builtin_amdgcn_s_setprio(1);
#pragma unroll
      for (int kt = 0; kt < 2; ++kt) {
        f16x8 pB[2];
#pragma unroll
        for (int mt = 0; mt < 2; ++mt) {
          int q = 16 * mt + lr;
          pB[mt] = *reinterpret_cast<const f16x8*>(
              &Ps[w][q * 64 + ((32 * kt + 8 * g) ^ ((q & 7) << 3))]);
        }
#pragma unroll
        for (int dt = 0; dt < 4; ++dt) {
          int d = 16 * dt + lr;
          int s = (d + (d >> 3)) & 7;
          f16x8 vA = *reinterpret_cast<const f16x8*>(
              &Vt[cur][d * 64 + ((32 * kt + 8 * g) ^ (s << 3))]);
#pragma unroll
          for (int mt = 0; mt < 2; ++mt)
            Ot[mt][dt] = __builtin_amdgcn_mfma_f32_16x16x32_f16(
                vA, pB[mt], Ot[mt][dt], 0, 0, 0);
        }
      }
      __builtin_amdgcn_s_setprio(0);
    }

    // ---- finalize segment: normalize, repack via Ps, coalesced stores ----
#pragma unroll
    for (int mt = 0; mt < 2; ++mt) {
      float inv = 1.f / l_run[mt];
      int q = 16 * mt + lr;
#pragma unroll
      for (int dt = 0; dt < 4; ++dt) {
        f16x4 ok;
#pragma unroll
        for (int r = 0; r < 4; ++r) ok[r] = (f16)(Ot[mt][dt][r] * inv);
        *reinterpret_cast<f16x4*>(
            &Ps[w][q * 64 + ((16 * dt + 4 * g) ^ ((q & 7) << 3))]) = ok;
      }
    }
    const int orow = l >> 1;
    const int ocol = (l & 1) * 32;
#pragma unroll
    for (int i = 0; i < 4; ++i) {
      f16x8 ov = *reinterpret_cast<const f16x8*>(
          &Ps[w][orow * 64 + ((ocol + i * 8) ^ ((orow & 7) << 3))]);
      *reinterpret_cast<f16x8*>(
          &att[((size_t)(ob * NT + qbase + orow)) * NC + oh * HS + ocol + i * 8]) = ov;
    }
  }
}

// ---------------------------------------------------------------------------
extern "C" void kernel_launch(void* const* d_in, const int* in_sizes, int n_in,
                              void* d_out, int out_size, void* d_ws, size_t ws_size,
                              hipStream_t stream)
{
  (void)in_sizes; (void)n_in; (void)out_size; (void)ws_size;
  const float* x     = (const float*)d_in[0];
  const float* Wqkv  = (const float*)d_in[1];
  const float* bqkv  = (const float*)d_in[2];
  const float* Wproj = (const float*)d_in[3];
  const float* bproj = (const float*)d_in[4];
  float* out = (float*)d_out;

  const size_t HE = (size_t)NB * NH * NT * HS;   // 8388608 elems per tensor
  f16* Qh  = (f16*)d_ws;
  f16* Kh  = Qh + HE;
  f16* Vh  = Kh + HE;
  f16* XA  = Vh + HE;            // Xh (pre-attn) aliases att (post-attn)
  f16* Wqt = XA + HE;            // 3072x1024
  f16* Wpt = Wqt + (size_t)3 * NC * NC;  // 1024x1024

  convert_x<<<dim3(Mtot * NC / (256 * 8)), 256, 0, stream>>>(x, XA);
  transpose_w<<<dim3(64, 16), 256, 0, stream>>>(Wqkv, Wproj, Wqt, Wpt);
  gemm_f16<0><<<dim3(64 * 24), 256, 0, stream>>>(XA, Wqt, bqkv, Qh, Kh, Vh, nullptr, 24);
  flash_attn<<<dim3(512), 256, 0, stream>>>(Qh, Kh, Vh, XA);
  gemm_f16<1><<<dim3(64 * 8), 256, 0, stream>>>(XA, Wpt, bproj, nullptr, nullptr, nullptr, out, 8);
}

// Round 7
// 188.756 us; speedup vs baseline: 8.2004x; 1.0144x over previous
//
#include <hip/hip_runtime.h>
#include <cstdint>

typedef _Float16 f16;
typedef _Float16 f16x4 __attribute__((ext_vector_type(4)));
typedef _Float16 f16x8 __attribute__((ext_vector_type(8)));
typedef float f32x4 __attribute__((ext_vector_type(4)));

constexpr int NB = 4, NT = 2048, NC = 1024, NH = 16, HS = 64;
constexpr int Mtot = NB * NT;            // 8192
constexpr int BM = 128, BN = 128;

// async global->LDS 16B (CK-style addrspace casts)
__device__ __forceinline__ void gll16(const f16* g, f16* l) {
  __builtin_amdgcn_global_load_lds(
      (const __attribute__((address_space(1))) unsigned int*)(uintptr_t)g,
      (__attribute__((address_space(3))) unsigned int*)(uintptr_t)l, 16, 0, 0);
}

// ---------------------------------------------------------------------------
// X fp32 -> f16 (same layout)
// ---------------------------------------------------------------------------
__global__ __launch_bounds__(256) void convert_x(
    const float* __restrict__ X, f16* __restrict__ Xh)
{
  const size_t i = ((size_t)blockIdx.x * 256 + threadIdx.x) * 8;
  float4 a = *reinterpret_cast<const float4*>(X + i);
  float4 b = *reinterpret_cast<const float4*>(X + i + 4);
  f16x8 o;
  o[0] = (f16)a.x; o[1] = (f16)a.y; o[2] = (f16)a.z; o[3] = (f16)a.w;
  o[4] = (f16)b.x; o[5] = (f16)b.y; o[6] = (f16)b.z; o[7] = (f16)b.w;
  *reinterpret_cast<f16x8*>(Xh + i) = o;
}

// ---------------------------------------------------------------------------
// W_qkv [1024][3072] & W_proj [1024][1024] fp32 -> transposed f16 [n][k]
// ---------------------------------------------------------------------------
__global__ __launch_bounds__(256) void transpose_w(
    const float* __restrict__ Wq, const float* __restrict__ Wp,
    f16* __restrict__ Wqt, f16* __restrict__ Wpt)
{
  __shared__ __align__(16) f16 Ts[64 * 72];
  const int bx = blockIdx.x;
  const float* src; f16* dst; int Ndim, n0;
  if (bx < 48) { src = Wq; dst = Wqt; Ndim = 3 * NC; n0 = bx * 64; }
  else         { src = Wp; dst = Wpt; Ndim = NC;     n0 = (bx - 48) * 64; }
  const int k0 = blockIdx.y * 64;
  const int t = threadIdx.x;
  const int kl = t >> 2, nb = (t & 3) * 16;
#pragma unroll
  for (int i = 0; i < 4; ++i) {
    float4 vv = *reinterpret_cast<const float4*>(
        src + (size_t)(k0 + kl) * Ndim + n0 + nb + 4 * i);
    f16x4 h; h[0] = (f16)vv.x; h[1] = (f16)vv.y; h[2] = (f16)vv.z; h[3] = (f16)vv.w;
    *reinterpret_cast<f16x4*>(&Ts[kl * 72 + nb + 4 * i]) = h;
  }
  __syncthreads();
  const int nl = t >> 2, kb = (t & 3) * 16;
#pragma unroll
  for (int i = 0; i < 2; ++i) {
    f16x8 o;
#pragma unroll
    for (int j = 0; j < 8; ++j) o[j] = Ts[(kb + 8 * i + j) * 72 + nl];
    *reinterpret_cast<f16x8*>(dst + (size_t)(n0 + nl) * NC + k0 + kb + 8 * i) = o;
  }
}

// ---------------------------------------------------------------------------
// f16 GEMM, 128x128 tile, BK=64, global_load_lds staging (pre-swizzled src).
// ---------------------------------------------------------------------------
template <int MODE>
__global__ __launch_bounds__(256) void gemm_f16(
    const f16* __restrict__ A, const f16* __restrict__ Bt,
    const float* __restrict__ bias,
    f16* __restrict__ Qh, f16* __restrict__ Kh, f16* __restrict__ Vh,
    float* __restrict__ Out, int ntiles)
{
  __shared__ __align__(16) f16 As[BM * 64];
  __shared__ __align__(16) f16 Bs[BN * 64];
  const int tid = threadIdx.x;
  const int flat = blockIdx.x;
  const int cpx = gridDim.x >> 3;
  const int v = (flat & 7) * cpx + (flat >> 3);       // XCD-contig chunks
  const int m0 = (v / ntiles) * BM;
  const int n0 = (v % ntiles) * BN;
  const int w = tid >> 6, l = tid & 63;
  const int wr = w >> 1, wc = w & 1;
  const int lr = l & 15, hi = l >> 4;

  f32x4 acc[4][4];
#pragma unroll
  for (int i = 0; i < 4; ++i)
#pragma unroll
    for (int j = 0; j < 4; ++j) acc[i][j] = (f32x4){0.f, 0.f, 0.f, 0.f};

  const int lrow = l >> 3;
  const int lsrc = ((l & 7) ^ lrow) * 8;

  for (int k0 = 0; k0 < NC; k0 += 64) {
    __syncthreads();
#pragma unroll
    for (int i = 0; i < 4; ++i) {
      const int rr = 32 * w + 8 * i;
      gll16(A  + (size_t)(m0 + rr + lrow) * NC + k0 + lsrc, &As[rr * 64]);
      gll16(Bt + (size_t)(n0 + rr + lrow) * NC + k0 + lsrc, &Bs[rr * 64]);
    }
    __syncthreads();
#pragma unroll
    for (int kk = 0; kk < 2; ++kk) {
      f16x8 a[4], b[4];
#pragma unroll
      for (int mi = 0; mi < 4; ++mi) {
        int row = wr * 64 + mi * 16 + lr;
        int idx = (row * 64 + kk * 32 + hi * 8) ^ ((row & 7) << 3);
        a[mi] = *reinterpret_cast<const f16x8*>(&As[idx]);
      }
#pragma unroll
      for (int ni = 0; ni < 4; ++ni) {
        int row = wc * 64 + ni * 16 + lr;
        int idx = (row * 64 + kk * 32 + hi * 8) ^ ((row & 7) << 3);
        b[ni] = *reinterpret_cast<const f16x8*>(&Bs[idx]);
      }
#pragma unroll
      for (int mi = 0; mi < 4; ++mi)
#pragma unroll
        for (int ni = 0; ni < 4; ++ni)
          acc[mi][ni] = __builtin_amdgcn_mfma_f32_16x16x32_f16(
              a[mi], b[ni], acc[mi][ni], 0, 0, 0);
    }
  }

  if (MODE == 0) {
#pragma unroll
    for (int ni = 0; ni < 4; ++ni) {
      int colg = n0 + wc * 64 + ni * 16 + lr;
      int which = colg >> 10;
      int c = colg & (NC - 1);
      int h = c >> 6, d = c & 63;
      f16* dst = (which == 0) ? Qh : ((which == 1) ? Kh : Vh);
      float bv = bias[colg];
#pragma unroll
      for (int mi = 0; mi < 4; ++mi) {
#pragma unroll
        for (int r = 0; r < 4; ++r) {
          int rowg = m0 + wr * 64 + mi * 16 + hi * 4 + r;
          int b = rowg >> 11, t = rowg & (NT - 1);
          dst[(((size_t)(b * NH + h) * NT) + t) * HS + d] =
              (f16)(acc[mi][ni][r] + bv);
        }
      }
    }
  } else {
#pragma unroll
    for (int ni = 0; ni < 4; ++ni) {
      int colg = n0 + wc * 64 + ni * 16 + lr;
      float bv = bias[colg];
#pragma unroll
      for (int mi = 0; mi < 4; ++mi) {
#pragma unroll
        for (int r = 0; r < 4; ++r) {
          int rowg = m0 + wr * 64 + mi * 16 + hi * 4 + r;
          Out[(size_t)rowg * NC + colg] = acc[mi][ni][r] + bv;
        }
      }
    }
  }
}

// ---------------------------------------------------------------------------
// MFMA flash attention, causal. Block = 4 waves x 128 q-rows; block does the
// q-tile pair {qt, 15-qt} (uniform 34 kv-tiles). KV tile = 64, double-buffered.
// Swapped QK^T (St = K.Q^T). V rows stored tau-permuted in Vt so the softmax
// C-layout registers feed PV's B-operand DIRECTLY (no P LDS round-trip):
//   tau: kv=[b5|b4|b3b2|b1b0] -> slot=[b5|b3b2|b4|b1b0];  pB[kt]=concat(p[2kt],p[2kt+1])
// LDS = 32 KiB (Ks+Vt only); epilogue repack aliases Ks. Defer-max (THR=8).
// ---------------------------------------------------------------------------
__global__ __launch_bounds__(256, 2) void flash_attn(
    const f16* __restrict__ Qh, const f16* __restrict__ Kh,
    const f16* __restrict__ Vh, f16* __restrict__ att)
{
  __shared__ __align__(16) f16 Ks[2][64 * 64];   // [kv][d], d-swizzled by row
  __shared__ __align__(16) f16 Vt[2][64 * 64];   // [d][slot], slot-swizzled by d

  const int tid = threadIdx.x;
  const int w = tid >> 6, l = tid & 63;
  const int lr = l & 15, g = l >> 4;

  const int flat = blockIdx.x;                    // 0..511
  const int v = (flat & 7) * 64 + (flat >> 3);    // XCD-contig chunks
  const int pairi = v & 7;                        // 0..7
  const int bh = v >> 3;                          // 0..63

  const f16* Qb = Qh + (size_t)bh * NT * HS;
  const f16* Kb = Kh + (size_t)bh * NT * HS;
  const f16* Vb = Vh + (size_t)bh * NT * HS;
  const int ob = bh >> 4, oh = bh & (NH - 1);

  const int srow = tid >> 2;            // 0..63
  const int scol = (tid & 3) * 16;      // 0,16,32,48
  // tau(srow): V row -> PV k-slot
  const int ksl = ((srow >> 5) & 1) * 32 + ((srow >> 2) & 3) * 8 +
                  ((srow >> 4) & 1) * 4 + (srow & 3);

  f16x8 kpre[2], vpre[2];
#pragma unroll
  for (int ii = 0; ii < 2; ++ii) {
    kpre[ii] = *reinterpret_cast<const f16x8*>(Kb + (size_t)srow * HS + scol + 8 * ii);
    vpre[ii] = *reinterpret_cast<const f16x8*>(Vb + (size_t)srow * HS + scol + 8 * ii);
  }

  for (int seg = 0; seg < 2; ++seg) {
    const int qt = (seg == 0) ? pairi : 15 - pairi;
    const int qbase = qt * 128 + w * 32;
    const int jtmax = 2 * qt + 1;

    // Q as B-operand fragments (col=lr, k=8g+j), scale (1/8)*log2(e) folded
    f16x8 qB[2][2];
#pragma unroll
    for (int mt = 0; mt < 2; ++mt)
#pragma unroll
      for (int ds = 0; ds < 2; ++ds) {
        f16x8 t = *reinterpret_cast<const f16x8*>(
            Qb + (size_t)(qbase + 16 * mt + lr) * HS + 32 * ds + 8 * g);
#pragma unroll
        for (int j = 0; j < 8; ++j) t[j] = t[j] * (f16)0.18033688f;
        qB[mt][ds] = t;
      }

    f32x4 Ot[2][4];
    float m_run[2], l_run[2];
#pragma unroll
    for (int mt = 0; mt < 2; ++mt) {
#pragma unroll
      for (int dt = 0; dt < 4; ++dt) Ot[mt][dt] = (f32x4){0.f, 0.f, 0.f, 0.f};
      m_run[mt] = -INFINITY; l_run[mt] = 0.f;
    }

    for (int jt = 0; jt <= jtmax; ++jt) {
      const int cur = jt & 1;
      // ---- commit prefetched tile to LDS ----
#pragma unroll
      for (int ii = 0; ii < 2; ++ii) {
        int c0 = scol + 8 * ii;
        *reinterpret_cast<f16x8*>(&Ks[cur][srow * 64 + (c0 ^ ((srow & 7) << 3))]) = kpre[ii];
#pragma unroll
        for (int j = 0; j < 8; ++j) {
          int d = c0 + j;
          int s = (d + (d >> 3)) & 7;
          Vt[cur][d * 64 + (ksl ^ (s << 3))] = vpre[ii][j];
        }
      }
      // ---- issue next tile's global loads ----
      const bool more = (jt < jtmax) || (seg == 0);
      if (more) {
        const int nj = (jt < jtmax) ? jt + 1 : 0;
#pragma unroll
        for (int ii = 0; ii < 2; ++ii) {
          kpre[ii] = *reinterpret_cast<const f16x8*>(
              Kb + (size_t)(nj * 64 + srow) * HS + scol + 8 * ii);
          vpre[ii] = *reinterpret_cast<const f16x8*>(
              Vb + (size_t)(nj * 64 + srow) * HS + scol + 8 * ii);
        }
      }
      __syncthreads();

      if (jt * 64 > qbase + 31) continue;   // wave fully masked for this tile

      const bool needMask = (jt * 64 + 63) > qbase;

      // ---- cache K fragments (A-operand) in registers, once per tile ----
      f16x8 aK[4][2];
#pragma unroll
      for (int kt2 = 0; kt2 < 4; ++kt2) {
        int row = 16 * kt2 + lr;
#pragma unroll
        for (int ds = 0; ds < 2; ++ds)
          aK[kt2][ds] = *reinterpret_cast<const f16x8*>(
              &Ks[cur][row * 64 + ((32 * ds + 8 * g) ^ ((row & 7) << 3))]);
      }

      f16x8 pB[2][2];   // [mt][kt] PV B-operand, assembled in-register

      // ---- per 16-q half-tile: St = K.Q^T, then online softmax ----
#pragma unroll
      for (int mt = 0; mt < 2; ++mt) {
        f32x4 St[4];
#pragma unroll
        for (int kt2 = 0; kt2 < 4; ++kt2) St[kt2] = (f32x4){0.f, 0.f, 0.f, 0.f};
        __builtin_amdgcn_s_setprio(1);
#pragma unroll
        for (int kt2 = 0; kt2 < 4; ++kt2)
#pragma unroll
          for (int ds = 0; ds < 2; ++ds)
            St[kt2] = __builtin_amdgcn_mfma_f32_16x16x32_f16(
                aK[kt2][ds], qB[mt][ds], St[kt2], 0, 0, 0);
        __builtin_amdgcn_s_setprio(0);

        const int qg = qbase + 16 * mt + lr;
        if (needMask) {
#pragma unroll
          for (int kt2 = 0; kt2 < 4; ++kt2)
#pragma unroll
            for (int r = 0; r < 4; ++r)
              if ((jt * 64 + 16 * kt2 + 4 * g + r) > qg) St[kt2][r] = -INFINITY;
        }
        float pm = -INFINITY;
#pragma unroll
        for (int kt2 = 0; kt2 < 4; ++kt2)
#pragma unroll
          for (int r = 0; r < 4; ++r) pm = fmaxf(pm, St[kt2][r]);
        pm = fmaxf(pm, __shfl_xor(pm, 16));
        pm = fmaxf(pm, __shfl_xor(pm, 32));
        float mo = m_run[mt];
        if (!__all(pm <= mo + 8.0f)) {       // defer-max: rescale only on growth
          float mn = fmaxf(mo, pm);
          float al = exp2f(mo - mn);
          l_run[mt] *= al;
#pragma unroll
          for (int dt = 0; dt < 4; ++dt)
#pragma unroll
            for (int r = 0; r < 4; ++r) Ot[mt][dt][r] *= al;
          m_run[mt] = mn;
          mo = mn;
        }
        float ts = 0.f;
#pragma unroll
        for (int kt2 = 0; kt2 < 4; ++kt2) {
#pragma unroll
          for (int r = 0; r < 4; ++r) {
            float pp = exp2f(St[kt2][r] - mo);
            ts += pp;
            pB[mt][kt2 >> 1][(kt2 & 1) * 4 + r] = (f16)pp;
          }
        }
        ts += __shfl_xor(ts, 16);
        ts += __shfl_xor(ts, 32);
        l_run[mt] += ts;
      }

      // ---- O^T += V~^T . P~^T  (P direct from registers, V tau-permuted) ----
      __builtin_amdgcn_s_setprio(1);
#pragma unroll
      for (int kt = 0; kt < 2; ++kt)
#pragma unroll
        for (int dt = 0; dt < 4; ++dt) {
          int d = 16 * dt + lr;
          int s = (d + (d >> 3)) & 7;
          f16x8 vA = *reinterpret_cast<const f16x8*>(
              &Vt[cur][d * 64 + ((32 * kt + 8 * g) ^ (s << 3))]);
#pragma unroll
          for (int mt = 0; mt < 2; ++mt)
            Ot[mt][dt] = __builtin_amdgcn_mfma_f32_16x16x32_f16(
                vA, pB[mt][kt], Ot[mt][dt], 0, 0, 0);
        }
      __builtin_amdgcn_s_setprio(0);
    }

    // ---- epilogue: normalize, repack via Ks-aliased scratch, store ----
    __syncthreads();                      // all waves done reading Ks/Vt
    f16* scr = &Ks[0][0] + w * 2048;      // per-wave 32x64 region
#pragma unroll
    for (int mt = 0; mt < 2; ++mt) {
      float inv = 1.f / l_run[mt];
      int q = 16 * mt + lr;
#pragma unroll
      for (int dt = 0; dt < 4; ++dt) {
        f16x4 ok;
#pragma unroll
        for (int r = 0; r < 4; ++r) ok[r] = (f16)(Ot[mt][dt][r] * inv);
        *reinterpret_cast<f16x4*>(
            &scr[q * 64 + ((16 * dt + 4 * g) ^ ((q & 7) << 3))]) = ok;
      }
    }
    const int orow = l >> 1;
    const int ocol = (l & 1) * 32;
#pragma unroll
    for (int i = 0; i < 4; ++i) {
      f16x8 ov = *reinterpret_cast<const f16x8*>(
          &scr[orow * 64 + ((ocol + i * 8) ^ ((orow & 7) << 3))]);
      *reinterpret_cast<f16x8*>(
          &att[((size_t)(ob * NT + qbase + orow)) * NC + oh * HS + ocol + i * 8]) = ov;
    }
    __syncthreads();                      // protect scratch before next commit
  }
}

// ---------------------------------------------------------------------------
extern "C" void kernel_launch(void* const* d_in, const int* in_sizes, int n_in,
                              void* d_out, int out_size, void* d_ws, size_t ws_size,
                              hipStream_t stream)
{
  (void)in_sizes; (void)n_in; (void)out_size; (void)ws_size;
  const float* x     = (const float*)d_in[0];
  const float* Wqkv  = (const float*)d_in[1];
  const float* bqkv  = (const float*)d_in[2];
  const float* Wproj = (const float*)d_in[3];
  const float* bproj = (const float*)d_in[4];
  float* out = (float*)d_out;

  const size_t HE = (size_t)NB * NH * NT * HS;   // 8388608 elems per tensor
  f16* Qh  = (f16*)d_ws;
  f16* Kh  = Qh + HE;
  f16* Vh  = Kh + HE;
  f16* XA  = Vh + HE;            // Xh (pre-attn) aliases att (post-attn)
  f16* Wqt = XA + HE;            // 3072x1024
  f16* Wpt = Wqt + (size_t)3 * NC * NC;  // 1024x1024

  convert_x<<<dim3(Mtot * NC / (256 * 8)), 256, 0, stream>>>(x, XA);
  transpose_w<<<dim3(64, 16), 256, 0, stream>>>(Wqkv, Wproj, Wqt, Wpt);
  gemm_f16<0><<<dim3(64 * 24), 256, 0, stream>>>(XA, Wqt, bqkv, Qh, Kh, Vh, nullptr, 24);
  flash_attn<<<dim3(512), 256, 0, stream>>>(Qh, Kh, Vh, XA);
  gemm_f16<1><<<dim3(64 * 8), 256, 0, stream>>>(XA, Wpt, bproj, nullptr, nullptr, nullptr, out, 8);
}